// Round 7
// baseline (596.996 us; speedup 1.0000x reference)
//
#include <hip/hip_runtime.h>
#include <hip/hip_fp16.h>

#define BF 256
#define TSTEPS 256

typedef _Float16 h8_t __attribute__((ext_vector_type(8)));
typedef _Float16 h4_t __attribute__((ext_vector_type(4)));
typedef float f4_t __attribute__((ext_vector_type(4)));

union H8 { uint4 u; h8_t v; };
union H4 { uint2 u; h4_t v; };
union U2H4 { uint2 u; __half h[4]; };

// fast sigmoid/tanh: v_exp + v_rcp (error << f16 storage quantization of h)
static __device__ __forceinline__ float sigmoidf_(float x) {
    return __builtin_amdgcn_rcpf(1.f + __expf(-x));
}
static __device__ __forceinline__ float tanhf_(float x) {
    return 1.f - 2.f * __builtin_amdgcn_rcpf(__expf(2.f * x) + 1.f);
}

// xor-32 lane exchange on the VALU (v_permlane32_swap_b32) instead of the LDS
// crossbar (ds_swizzle). Bit-exact vs __shfl_xor(x,32).
static __device__ __forceinline__ float xswap32(float x, int lane) {
    typedef unsigned uv2 __attribute__((ext_vector_type(2)));
    unsigned xu = __float_as_uint(x);
    uv2 r = __builtin_amdgcn_permlane32_swap(xu, xu, false, false);
    return __uint_as_float((lane & 32) ? r[0] : r[1]);
}

// LDS-only workgroup barrier: drains lgkmcnt (ds ops) but leaves vmcnt
// (global stores / prefetch loads) in flight across the barrier.
static __device__ __forceinline__ void wg_barrier_lds() {
    __builtin_amdgcn_sched_barrier(0);
    asm volatile("s_waitcnt lgkmcnt(0)" ::: "memory");
    __builtin_amdgcn_s_barrier();
    __builtin_amdgcn_sched_barrier(0);
}

// wave-local LDS fence: ensure this wave's ds_writes completed before its ds_reads.
static __device__ __forceinline__ void wave_lds_fence() {
    __builtin_amdgcn_sched_barrier(0);
    asm volatile("s_waitcnt lgkmcnt(0)" ::: "memory");
    __builtin_amdgcn_sched_barrier(0);
}

// ---- pack helper: f16 MFMA operand layout -----------------------------------------
static __device__ __forceinline__ void pack_one(const float* __restrict__ src,
                                                __half* __restrict__ dst,
                                                int OC, int IC, int KS,
                                                int oc_str, int ic_str, int k_str, int i) {
    int grp = KS / 4;
    int j = i % grp;
    int oc = (i / grp) % OC;
    int g = (i / (grp * OC)) & 3;
    int chunk = i / (grp * OC * 4);
    int CPK = IC / KS;
    int cc = chunk % CPK;
    int khw = chunk / CPK;
    int ic = cc * KS + g * grp + j;
    dst[i] = __float2half(src[(long)oc * oc_str + (long)ic * ic_str + khw * k_str]);
}

// Whh pack with class-interleaved row permutation: packed row prow = t*16 + cls*4 + du
// maps to original row cls*128 + t*4 + du. A 16-row MFMA tile then holds
// 4 classes x 4 units, so one wave (2 tiles) covers 8 units x all 4 classes.
static __device__ __forceinline__ void pack_whh_one(const float* __restrict__ src,
                                                    __half* __restrict__ dst, int i) {
    int j = i & 7;
    int prow = (i >> 3) & 511;
    int cg = i >> 12;            // chunk*4 + g
    int g = cg & 3, chunk = cg >> 2;
    int t = prow >> 4, rr = prow & 15;
    int cls = rr >> 2, du = rr & 3;
    int orig = cls * 128 + t * 4 + du;
    int ic = chunk * 32 + g * 8 + j;
    dst[i] = __float2half(src[orig * 128 + ic]);
}

// ---- fused weight prep ------------------------------------------------------------
__global__ __launch_bounds__(256) void prep_k(
        const float* __restrict__ w0, const float* __restrict__ w1,
        const float* __restrict__ w2, const float* __restrict__ w3,
        const float* __restrict__ Wihf, const float* __restrict__ Wihb,
        const float* __restrict__ Whhf, const float* __restrict__ Whhb,
        float* __restrict__ w0t, __half* __restrict__ w1p,
        __half* __restrict__ w2p, __half* __restrict__ w3p,
        __half* __restrict__ wfp, __half* __restrict__ wbp,
        __half* __restrict__ whhfp, __half* __restrict__ whhbp) {
    int i = blockIdx.x * 256 + threadIdx.x;
    if (i < 144) { int oc = i / 9, rem = i % 9; w0t[rem * 16 + oc] = w0[i]; return; }
    i -= 144;
    if (i < 4608) { pack_one(w1, w1p, 32, 16, 16, 144, 9, 1, i); return; }
    i -= 4608;
    if (i < 18432) { pack_one(w2, w2p, 64, 32, 32, 288, 9, 1, i); return; }
    i -= 18432;
    if (i < 73728) { pack_one(w3, w3p, 128, 64, 32, 576, 9, 1, i); return; }
    i -= 73728;
    if (i < 65536) { pack_one(Wihf, wfp, 512, 128, 32, 128, 1, 0, i); return; }
    i -= 65536;
    if (i < 65536) { pack_one(Wihb, wbp, 512, 128, 32, 128, 1, 0, i); return; }
    i -= 65536;
    if (i < 65536) { pack_whh_one(Whhf, whhfp, i); return; }
    i -= 65536;
    if (i < 65536) { pack_whh_one(Whhb, whhbp, i); return; }
}

// ---- conv0: 1->16 ch, VALU, NHWC f16 out (uint4-packed stores) --------------------
__global__ __launch_bounds__(256) void conv0_k(const float* __restrict__ in,
                                               const float* __restrict__ wT,
                                               const float* __restrict__ bias,
                                               __half* __restrict__ out) {
    __shared__ float wsm[9][16];
    __shared__ float bs[16];
    int tid = threadIdx.x;
    if (tid < 144) wsm[tid / 16][tid % 16] = wT[tid];
    if (tid < 16) bs[tid] = bias[tid];
    __syncthreads();
    int gid = blockIdx.x * 256 + tid;
    int ow = gid % 27;
    int t = (gid / 27) % 256;
    int bf = gid / (27 * 256);
    float acc[16];
#pragma unroll
    for (int o = 0; o < 16; o++) acc[o] = bs[o];
    int iw0 = ow * 3 - 1;
#pragma unroll
    for (int kh = 0; kh < 3; kh++) {
        int tt = t + kh - 1;
        if ((unsigned)tt >= 256u) continue;
        const float* ip = in + ((long)bf * 256 + tt) * 81;
#pragma unroll
        for (int kw = 0; kw < 3; kw++) {
            int iw = iw0 + kw;
            if ((unsigned)iw >= 81u) continue;
            float x = ip[iw];
#pragma unroll
            for (int o = 0; o < 16; o++) acc[o] += x * wsm[kh * 3 + kw][o];
        }
    }
    union OU { uint4 u; __half2 h2[4]; } o0, o1;
#pragma unroll
    for (int o = 0; o < 4; o++)
        o0.h2[o] = __floats2half2_rn(fmaxf(acc[2 * o], 0.f), fmaxf(acc[2 * o + 1], 0.f));
#pragma unroll
    for (int o = 0; o < 4; o++)
        o1.h2[o] = __floats2half2_rn(fmaxf(acc[8 + 2 * o], 0.f), fmaxf(acc[9 + 2 * o], 0.f));
    uint4* op = (uint4*)(out + (long)gid * 16);
    op[0] = o0.u;
    op[1] = o1.u;
}

// ---- MFMA implicit-GEMM conv: NHWC f16 in/out (used for conv1, conv2) -------------
template<int IC, int OC, int WIN, int WOUT, int KS>
__global__ __launch_bounds__(256) void convM_k(const __half* __restrict__ in,
                                               const __half* __restrict__ wp,
                                               const float* __restrict__ bias,
                                               __half* __restrict__ out) {
    constexpr int NT = OC / 16;
    constexpr int CPK = IC / KS;
    constexpr int NCHUNK = 9 * CPK;
    constexpr int GRP = KS / 4;
    int tid = threadIdx.x;
    int lane = tid & 63;
    int wv = tid >> 6;
    int l15 = lane & 15;
    int g = lane >> 4;
    int m = blockIdx.x * 64 + wv * 16 + l15;
    int ow = m % WOUT;
    int t = (m / WOUT) % 256;
    int bf = m / (WOUT * 256);

    f4_t acc[NT];
#pragma unroll
    for (int nt = 0; nt < NT; nt++)
#pragma unroll
        for (int r = 0; r < 4; r++) acc[nt][r] = 0.f;

#pragma unroll
    for (int chunk = 0; chunk < NCHUNK; chunk++) {
        int khw = chunk / CPK, cc = chunk % CPK;
        int kh = khw / 3;
        int kw = khw - kh * 3;
        int tt = t + kh - 1;
        int iw = ow * 3 + kw - 1;
        bool ok = ((unsigned)tt < 256u) && ((unsigned)iw < (unsigned)WIN);
        long aoff = ok ? (((long)(bf * 256 + tt) * WIN + iw) * IC + cc * KS + g * GRP) : 0;
        if constexpr (KS == 32) {
            H8 af;
            af.u = *(const uint4*)(in + aoff);
            if (!ok) af.u = make_uint4(0u, 0u, 0u, 0u);
#pragma unroll
            for (int nt = 0; nt < NT; nt++) {
                H8 bf8;
                bf8.u = *(const uint4*)(wp + ((long)(chunk * 4 + g) * OC + nt * 16 + l15) * GRP);
                acc[nt] = __builtin_amdgcn_mfma_f32_16x16x32_f16(af.v, bf8.v, acc[nt], 0, 0, 0);
            }
        } else {
            H4 af;
            af.u = *(const uint2*)(in + aoff);
            if (!ok) af.u = make_uint2(0u, 0u);
#pragma unroll
            for (int nt = 0; nt < NT; nt++) {
                H4 bf4;
                bf4.u = *(const uint2*)(wp + ((long)(chunk * 4 + g) * OC + nt * 16 + l15) * GRP);
                acc[nt] = __builtin_amdgcn_mfma_f32_16x16x16f16(af.v, bf4.v, acc[nt], 0, 0, 0);
            }
        }
    }
    int orow = blockIdx.x * 64 + wv * 16 + g * 4;
#pragma unroll
    for (int nt = 0; nt < NT; nt++) {
        int oc = nt * 16 + l15;
        float b = bias[oc];
#pragma unroll
        for (int r = 0; r < 4; r++) {
            float v = fmaxf(acc[nt][r] + b, 0.f);
            out[(long)(orow + r) * OC + oc] = __float2half(v);
        }
    }
}

// ---- FUSED conv3 + gates ----------------------------------------------------------
// Phase 1: conv3 (64->128ch, W 3->1) computes the block's X-tile [64 t x 128 c],
// kept in LDS (XOR-swizzled: col ^= (row&7)<<3 to kill the 16-way column conflict).
// Phase 2: gates GEMM X[64x128] @ Wih[128x1024] (wave wv owns cols wv*256..+256;
// wv 0,1 = fwd, wv 2,3 = bwd), bias added, staged per-wave transposed, written to
// G coalesced (128B runs per gate-row; bwd time-reversal folded into staging).
// Eliminates: X write (16.8MB), gates' 4x X re-read (67MB), one kernel launch.
__global__ __launch_bounds__(256) void c3g_k(const __half* __restrict__ in,
                                             const __half* __restrict__ wp3,
                                             const float* __restrict__ bias3,
                                             const __half* __restrict__ wpf,
                                             const __half* __restrict__ wpb,
                                             const float* __restrict__ bf1,
                                             const float* __restrict__ bf2,
                                             const float* __restrict__ bb1,
                                             const float* __restrict__ bb2,
                                             __half* __restrict__ Gf,
                                             __half* __restrict__ Gb) {
    int tid = threadIdx.x;
    int lane = tid & 63;
    int wv = tid >> 6;
    int l15 = lane & 15;
    int g = lane >> 4;

    __shared__ __align__(16) __half Xs[64 * 128];
    __shared__ __align__(16) __half sh[4][64][72];

    // ---- phase 1: conv3 (IC=64, OC=128, WIN=3, WOUT=1, KS=32) ----
    {
        int m = blockIdx.x * 64 + wv * 16 + l15;
        int t = m % 256;
        int bf = m / 256;
        f4_t acc[8];
#pragma unroll
        for (int nt = 0; nt < 8; nt++)
#pragma unroll
            for (int r = 0; r < 4; r++) acc[nt][r] = 0.f;

#pragma unroll
        for (int chunk = 0; chunk < 18; chunk++) {
            int khw = chunk / 2, cc = chunk % 2;
            int kh = khw / 3;
            int kw = khw - kh * 3;
            int tt = t + kh - 1;
            int iw = kw - 1;
            bool ok = ((unsigned)tt < 256u) && ((unsigned)iw < 3u);
            long aoff = ok ? (((long)(bf * 256 + tt) * 3 + iw) * 64 + cc * 32 + g * 8) : 0;
            H8 af;
            af.u = *(const uint4*)(in + aoff);
            if (!ok) af.u = make_uint4(0u, 0u, 0u, 0u);
#pragma unroll
            for (int nt = 0; nt < 8; nt++) {
                H8 bf8;
                bf8.u = *(const uint4*)(wp3 + ((long)(chunk * 4 + g) * 128 + nt * 16 + l15) * 8);
                acc[nt] = __builtin_amdgcn_mfma_f32_16x16x32_f16(af.v, bf8.v, acc[nt], 0, 0, 0);
            }
        }
        // epilogue -> LDS Xs, swizzled
#pragma unroll
        for (int nt = 0; nt < 8; nt++) {
            int col = nt * 16 + l15;
            float b = bias3[col];
#pragma unroll
            for (int r = 0; r < 4; r++) {
                int row = wv * 16 + g * 4 + r;
                float v = fmaxf(acc[nt][r] + b, 0.f);
                Xs[row * 128 + (col ^ ((row & 7) << 3))] = __float2half(v);
            }
        }
    }
    __syncthreads();

    // ---- phase 2: gates ----
    int dir = wv >> 1;
    int seq = blockIdx.x >> 2;
    int t0 = (blockIdx.x & 3) * 64;
    const __half* wpd = dir ? wpb : wpf;
    const float* bA = dir ? bb1 : bf1;
    const float* bB = dir ? bb2 : bf2;
    __half* Gd = dir ? Gb : Gf;

    // A-frags from swizzled Xs: af[rt][c].v[j] = X[rt*16+l15][c*32+g*8+j]
    H8 af2[4][4];
#pragma unroll
    for (int rt = 0; rt < 4; rt++) {
        int row = rt * 16 + l15;
        int base = row * 128;
        int sw = (l15 & 7) << 3;
#pragma unroll
        for (int c = 0; c < 4; c++)
            af2[rt][c].u = *(const uint4*)&Xs[base + ((c * 32 + g * 8) ^ sw)];
    }

    int ts0 = dir ? (192 - t0) : t0;
#pragma unroll
    for (int cb = 0; cb < 4; cb++) {
        int cbase = wv * 256 + cb * 64;          // global col base (0..1023)
        f4_t a2[4][4];
#pragma unroll
        for (int rt = 0; rt < 4; rt++)
#pragma unroll
            for (int ct = 0; ct < 4; ct++)
#pragma unroll
                for (int r = 0; r < 4; r++) a2[rt][ct][r] = 0.f;

#pragma unroll
        for (int c = 0; c < 4; c++) {
            H8 bw[4];
#pragma unroll
            for (int ct = 0; ct < 4; ct++) {
                int gcol = cbase + ct * 16 + l15 - dir * 512;
                bw[ct].u = *(const uint4*)(wpd + ((long)((c * 4 + g) * 512 + gcol)) * 8);
            }
#pragma unroll
            for (int rt = 0; rt < 4; rt++)
#pragma unroll
                for (int ct = 0; ct < 4; ct++)
                    a2[rt][ct] = __builtin_amdgcn_mfma_f32_16x16x32_f16(
                        af2[rt][c].v, bw[ct].v, a2[rt][ct], 0, 0, 0);
        }

        // stage transposed (bwd: time-reversed)
#pragma unroll
        for (int ct = 0; ct < 4; ct++) {
            int gcol = cbase + ct * 16 + l15 - dir * 512;
            float bias = bA[gcol] + bB[gcol];
            int col_lb = ct * 16 + l15;
#pragma unroll
            for (int rt = 0; rt < 4; rt++) {
                int tl2 = rt * 16 + g * 4;
#pragma unroll
                for (int rp = 0; rp < 4; rp += 2) {
                    __half2 h2;
                    int pos;
                    if (!dir) {
                        h2 = __floats2half2_rn(a2[rt][ct][rp] + bias, a2[rt][ct][rp + 1] + bias);
                        pos = tl2 + rp;
                    } else {
                        h2 = __floats2half2_rn(a2[rt][ct][rp + 1] + bias, a2[rt][ct][rp] + bias);
                        pos = 62 - (tl2 + rp);
                    }
                    *(__half2*)&sh[wv][col_lb][pos] = h2;
                }
            }
        }
        wave_lds_fence();
        // coalesced write-out: 64 cols x 128B runs
#pragma unroll
        for (int k = 0; k < 8; k++) {
            int idx = k * 64 + lane;
            int col_lb = idx >> 3;
            int ch = idx & 7;
            uint4 v = *(const uint4*)&sh[wv][col_lb][ch * 8];
            int gcol = cbase + col_lb - dir * 512;
            *(uint4*)(Gd + ((long)(seq * 512 + gcol)) * 256 + ts0 + ch * 8) = v;
        }
        wave_lds_fence();   // reads done before next batch overwrites staging
    }
}

// ---- LSTM recurrence: 256 blocks x 1024 thr (16 waves), 1 gate value per lane -----
// (unchanged — parked at ~183us; per-step serial skeleton is the floor)
__global__ __launch_bounds__(1024, 4) void lstm_k(const __half* __restrict__ Gf,
                                                  const __half* __restrict__ Gb,
                                                  const __half* __restrict__ whhfp,
                                                  const __half* __restrict__ whhbp,
                                                  __half* __restrict__ flat) {
    int bid = blockIdx.x;
    int dir = bid >> 7;
    int b0 = (bid & 127) * 2;
    const __half* G = dir ? Gb : Gf;
    const __half* wp = dir ? whhbp : whhfp;
    int tid = threadIdx.x;
    int w = tid >> 6;            // wave 0..15
    int lane = tid & 63;
    int l15 = lane & 15;
    int g2 = lane >> 4;          // class: 0=i, 1=f, 2=g, 3=o
    int chn = l15 >> 3;          // seq within block
    int u8 = l15 & 7;            // unit within wave's 8
    int unit = w * 8 + u8;       // 0..127
    int tsel = (u8 >> 2) & 1;
    int du = u8 & 3;

    // A-frags: 2 tiles x 4 k-chunks = 32 VGPRs/lane
    H8 afr[2][4];
#pragma unroll
    for (int t = 0; t < 2; t++) {
        int prow = (w * 2 + t) * 16 + l15;
#pragma unroll
        for (int c = 0; c < 4; c++)
            afr[t][c].u = *(const uint4*)(wp + ((long)((c * 4 + g2) * 512 + prow)) * 8);
    }

    __shared__ __align__(16) __half hbuf[2][2][128];
    if (tid < 256) hbuf[0][tid >> 7][tid & 127] = __float2half(0.f);
    __syncthreads();

    // this lane's single gate row in transposed G
    const __half* gb0 = G + (((long)(b0 + chn) * 512) + g2 * 128 + unit) * 256;

    float cst = 0.f;                         // cell state, valid on g2==1 lanes
    float ma = (g2 == 2) ? 2.f : 1.f;        // tanh(z) = 2*sigmoid(2z)-1 on g-lanes
    float mb = ma;
    float cb = (g2 == 2) ? -1.f : 0.f;
    const f4_t zero4 = {0.f, 0.f, 0.f, 0.f};

    H8 gc, gn;
    gc.u = *(const uint4*)(gb0);
    long fbase = (long)(b0 + chn) * 65536 + dir * 128 + unit;

    for (int to = 0; to < 32; to++) {
        if (to < 31) gn.u = *(const uint4*)(gb0 + (to + 1) * 8);
#pragma unroll
        for (int ti = 0; ti < 8; ti++) {
            int s = to * 8 + ti;
            int p = s & 1;
            H8 bfr[4];
#pragma unroll
            for (int c = 0; c < 4; c++)
                bfr[c].u = *(const uint4*)(&hbuf[p][chn][c * 32 + g2 * 8]);

            f4_t acc[2];
#pragma unroll
            for (int t = 0; t < 2; t++)
                acc[t] = __builtin_amdgcn_mfma_f32_16x16x32_f16(afr[t][0].v, bfr[0].v,
                                                                zero4, 0, 0, 0);
#pragma unroll
            for (int c = 1; c < 4; c++)
#pragma unroll
                for (int t = 0; t < 2; t++)
                    acc[t] = __builtin_amdgcn_mfma_f32_16x16x32_f16(afr[t][c].v, bfr[c].v,
                                                                    acc[t], 0, 0, 0);
            // select acc[tsel][du]
            f4_t at;
#pragma unroll
            for (int e = 0; e < 4; e++) at[e] = tsel ? acc[1][e] : acc[0][e];
            float lo = (du & 1) ? at[1] : at[0];
            float hi = (du & 1) ? at[3] : at[2];
            float ev = (du & 2) ? hi : lo;

            float z = ev + (float)gc.v[ti];
            float a = sigmoidf_(ma * z) * mb + cb;   // i,f,o: sigmoid; g: tanh

            float x1 = xswap32(a, lane);             // i<->g, f<->o (VALU permlane)
            float pi = a * x1;                       // on g2=0: sig(i)*tanh(g)
            float x2 = __shfl_xor(pi, 16, 64);       // g2=1 <- g2=0
            float cn = a * cst + x2;                 // on g2=1: sig(f)*c + pi
            cst = cn;
            float tc = tanhf_(cn);
            float x3 = xswap32(tc, lane);            // g2=3 <- g2=1 (VALU permlane)
            float h = a * x3;                        // on g2=3: sig(o)*tanh(c')

            if (g2 == 3) {
                __half hh = __float2half(h);
                int ts = dir ? (255 - s) : s;
                hbuf[p ^ 1][chn][unit] = hh;
                flat[fbase + (long)ts * 256] = hh;
            }
            wg_barrier_lds();
        }
        gc = gn;
    }
}

// ---- FC1 MFMA split-K: z[256][128] += flat16 @ fc1_w^T (fp32 weights, inline cvt) -
__global__ __launch_bounds__(256) void fc1m_k(const __half* __restrict__ flat,
                                              const float* __restrict__ fc1w,
                                              float* __restrict__ z) {
    int tid = threadIdx.x;
    int lane = tid & 63;
    int wv = tid >> 6;
    int l15 = lane & 15;
    int g = lane >> 4;
    int m0 = blockIdx.x * 64 + wv * 16;
    long k0 = (long)blockIdx.y * 1024;

    f4_t acc[8];
#pragma unroll
    for (int nt = 0; nt < 8; nt++)
#pragma unroll
        for (int r = 0; r < 4; r++) acc[nt][r] = 0.f;

    for (int c = 0; c < 32; c++) {
        H8 af;
        af.u = *(const uint4*)(flat + (long)(m0 + l15) * 65536 + k0 + c * 32 + g * 8);
#pragma unroll
        for (int nt = 0; nt < 8; nt++) {
            int oc = nt * 16 + l15;
            const float* wr = fc1w + (long)oc * 65536 + k0 + c * 32 + g * 8;
            float4 w0v = *(const float4*)(wr);
            float4 w1v = *(const float4*)(wr + 4);
            union { uint4 u; __half2 h2[4]; } bwc;
            bwc.h2[0] = __half2(__float2half(w0v.x), __float2half(w0v.y));
            bwc.h2[1] = __half2(__float2half(w0v.z), __float2half(w0v.w));
            bwc.h2[2] = __half2(__float2half(w1v.x), __float2half(w1v.y));
            bwc.h2[3] = __half2(__float2half(w1v.z), __float2half(w1v.w));
            H8 bw;
            bw.u = bwc.u;
            acc[nt] = __builtin_amdgcn_mfma_f32_16x16x32_f16(af.v, bw.v, acc[nt], 0, 0, 0);
        }
    }
#pragma unroll
    for (int nt = 0; nt < 8; nt++)
#pragma unroll
        for (int r = 0; r < 4; r++)
            atomicAdd(&z[(m0 + g * 4 + r) * 128 + nt * 16 + l15], acc[nt][r]);
}

__global__ void zero_k(float* __restrict__ p, int n) {
    int i = blockIdx.x * 256 + threadIdx.x;
    if (i < n) p[i] = 0.f;
}

// ---- head -------------------------------------------------------------------------
__global__ __launch_bounds__(256) void head_k(const float* __restrict__ z,
                                              const float* __restrict__ b1,
                                              const float* __restrict__ fsw,
                                              const float* __restrict__ fsb,
                                              float* __restrict__ out) {
    __shared__ float sf[256];
    int r = threadIdx.x;
    float acc = fsb[0];
#pragma unroll
    for (int j4 = 0; j4 < 32; j4++) {
        float4 zv = *(const float4*)&z[r * 128 + j4 * 4];
        float4 bv = *(const float4*)&b1[j4 * 4];
        float4 wv = *(const float4*)&fsw[j4 * 4];
        acc += fmaxf(zv.x + bv.x, 0.f) * wv.x;
        acc += fmaxf(zv.y + bv.y, 0.f) * wv.y;
        acc += fmaxf(zv.z + bv.z, 0.f) * wv.z;
        acc += fmaxf(zv.w + bv.w, 0.f) * wv.w;
    }
    float val = sigmoidf_(acc) * 4.f + 1.f;
    out[16 + r] = val;
    sf[r] = val;
    __syncthreads();
    if (r < 16) {
        float m = 0.f;
#pragma unroll
        for (int f = 0; f < 16; f++) m += sf[r * 16 + f];
        out[r] = m * (1.f / 16.f);
    }
}

extern "C" void kernel_launch(void* const* d_in, const int* in_sizes, int n_in,
                              void* d_out, int out_size, void* d_ws, size_t ws_size,
                              hipStream_t stream) {
    const float* audio = (const float*)d_in[0];
    const float* w0 = (const float*)d_in[2];
    const float* b0 = (const float*)d_in[3];
    const float* w1 = (const float*)d_in[4];
    const float* b1 = (const float*)d_in[5];
    const float* w2 = (const float*)d_in[6];
    const float* b2 = (const float*)d_in[7];
    const float* w3 = (const float*)d_in[8];
    const float* b3 = (const float*)d_in[9];
    const float* Wih_f = (const float*)d_in[10];
    const float* Whh_f = (const float*)d_in[11];
    const float* bih_f = (const float*)d_in[12];
    const float* bhh_f = (const float*)d_in[13];
    const float* Wih_b = (const float*)d_in[14];
    const float* Whh_b = (const float*)d_in[15];
    const float* bih_b = (const float*)d_in[16];
    const float* bhh_b = (const float*)d_in[17];
    const float* fc1_w = (const float*)d_in[18];
    const float* fc1_b = (const float*)d_in[19];
    const float* fs_w = (const float*)d_in[20];
    const float* fs_b = (const float*)d_in[21];
    float* out = (float*)d_out;

    char* ws = (char*)d_ws;
    // lifetimes: out1 dies before Gf; out0 dies before flat16
    __half* Gf    = (__half*)(ws);                    // 67.1 MB (transposed layout)
    __half* out1  = (__half*)(ws);                    // 37.7 MB (pre-Gf)
    __half* Gb    = (__half*)(ws + 67108864);         // 67.1 MB
    __half* flat16= (__half*)(ws + 134217728);        // 33.6 MB
    __half* out0  = (__half*)(ws + 134217728);        // 56.6 MB (pre-flat16)
    __half* out2  = (__half*)(ws + 218103808);        // 25.2 MB
    char* rd = ws + 243269632;
    float*  w0t   = (float*)(rd);
    __half* w1p   = (__half*)(rd + 1024);
    __half* w2p   = (__half*)(rd + 10240);
    __half* w3p   = (__half*)(rd + 47104);
    __half* wfp   = (__half*)(rd + 194560);
    __half* wbp   = (__half*)(rd + 325632);
    __half* whhfp = (__half*)(rd + 456704);
    __half* whhbp = (__half*)(rd + 587776);
    float*  zbuf  = (float*)(rd + 718848);

    // fused weight prep (1 launch)
    prep_k<<<1403, 256, 0, stream>>>(w0, w1, w2, w3, Wih_f, Wih_b, Whh_f, Whh_b,
                                     w0t, w1p, w2p, w3p, wfp, wbp, whhfp, whhbp);

    // conv chain (NHWC f16)
    conv0_k<<<6912, 256, 0, stream>>>(audio, w0t, b0, out0);
    convM_k<16, 32, 27, 9, 16><<<9216, 256, 0, stream>>>(out0, w1p, b1, out1);
    convM_k<32, 64, 9, 3, 32><<<3072, 256, 0, stream>>>(out1, w2p, b2, out2);

    // fused conv3 + gates (X stays in LDS; transposed coalesced G output)
    c3g_k<<<1024, 256, 0, stream>>>(out2, w3p, b3, wfp, wbp,
                                    bih_f, bhh_f, bih_b, bhh_b, Gf, Gb);

    // recurrence (16 waves, 1 gate value/lane, permlane stitches, 1 lgkm barrier/step)
    lstm_k<<<256, 1024, 0, stream>>>(Gf, Gb, whhfp, whhbp, flat16);

    // FC head: split-K MFMA reading fc1_w fp32 directly (inline f16 cvt), then head
    zero_k<<<128, 256, 0, stream>>>(zbuf, 256 * 128);
    fc1m_k<<<dim3(4, 64), 256, 0, stream>>>(flat16, fc1_w, zbuf);
    head_k<<<1, 256, 0, stream>>>(zbuf, fc1_b, fs_w, fs_b, out);
}

// Round 8
// 538.447 us; speedup vs baseline: 1.1087x; 1.1087x over previous
//
#include <hip/hip_runtime.h>
#include <hip/hip_fp16.h>

#define BF 256
#define TSTEPS 256

typedef _Float16 h8_t __attribute__((ext_vector_type(8)));
typedef _Float16 h4_t __attribute__((ext_vector_type(4)));
typedef float f4_t __attribute__((ext_vector_type(4)));

union H8 { uint4 u; h8_t v; };
union H4 { uint2 u; h4_t v; };
union U2H4 { uint2 u; __half h[4]; };

// fast sigmoid/tanh: v_exp + v_rcp (error << f16 storage quantization of h)
static __device__ __forceinline__ float sigmoidf_(float x) {
    return __builtin_amdgcn_rcpf(1.f + __expf(-x));
}
static __device__ __forceinline__ float tanhf_(float x) {
    return 1.f - 2.f * __builtin_amdgcn_rcpf(__expf(2.f * x) + 1.f);
}

// xor-32 lane exchange on the VALU (v_permlane32_swap_b32) instead of the LDS
// crossbar (ds_swizzle). Bit-exact vs __shfl_xor(x,32).
static __device__ __forceinline__ float xswap32(float x, int lane) {
    typedef unsigned uv2 __attribute__((ext_vector_type(2)));
    unsigned xu = __float_as_uint(x);
    uv2 r = __builtin_amdgcn_permlane32_swap(xu, xu, false, false);
    return __uint_as_float((lane & 32) ? r[0] : r[1]);
}

// LDS-only workgroup barrier: drains lgkmcnt (ds ops) but leaves vmcnt
// (global stores of h / G-prefetch loads) in flight across the barrier.
static __device__ __forceinline__ void wg_barrier_lds() {
    __builtin_amdgcn_sched_barrier(0);
    asm volatile("s_waitcnt lgkmcnt(0)" ::: "memory");
    __builtin_amdgcn_s_barrier();
    __builtin_amdgcn_sched_barrier(0);
}

// ---- pack helper: f16 MFMA operand layout -----------------------------------------
static __device__ __forceinline__ void pack_one(const float* __restrict__ src,
                                                __half* __restrict__ dst,
                                                int OC, int IC, int KS,
                                                int oc_str, int ic_str, int k_str, int i) {
    int grp = KS / 4;
    int j = i % grp;
    int oc = (i / grp) % OC;
    int g = (i / (grp * OC)) & 3;
    int chunk = i / (grp * OC * 4);
    int CPK = IC / KS;
    int cc = chunk % CPK;
    int khw = chunk / CPK;
    int ic = cc * KS + g * grp + j;
    dst[i] = __float2half(src[(long)oc * oc_str + (long)ic * ic_str + khw * k_str]);
}

// Whh pack with class-interleaved row permutation: packed row prow = t*16 + cls*4 + du
// maps to original row cls*128 + t*4 + du. A 16-row MFMA tile then holds
// 4 classes x 4 units, so one wave (2 tiles) covers 8 units x all 4 classes.
static __device__ __forceinline__ void pack_whh_one(const float* __restrict__ src,
                                                    __half* __restrict__ dst, int i) {
    int j = i & 7;
    int prow = (i >> 3) & 511;
    int cg = i >> 12;            // chunk*4 + g
    int g = cg & 3, chunk = cg >> 2;
    int t = prow >> 4, rr = prow & 15;
    int cls = rr >> 2, du = rr & 3;
    int orig = cls * 128 + t * 4 + du;
    int ic = chunk * 32 + g * 8 + j;
    dst[i] = __float2half(src[orig * 128 + ic]);
}

// ---- fused weight prep ------------------------------------------------------------
__global__ __launch_bounds__(256) void prep_k(
        const float* __restrict__ w0, const float* __restrict__ w1,
        const float* __restrict__ w2, const float* __restrict__ w3,
        const float* __restrict__ Wihf, const float* __restrict__ Wihb,
        const float* __restrict__ Whhf, const float* __restrict__ Whhb,
        float* __restrict__ w0t, __half* __restrict__ w1p,
        __half* __restrict__ w2p, __half* __restrict__ w3p,
        __half* __restrict__ wfp, __half* __restrict__ wbp,
        __half* __restrict__ whhfp, __half* __restrict__ whhbp) {
    int i = blockIdx.x * 256 + threadIdx.x;
    if (i < 144) { int oc = i / 9, rem = i % 9; w0t[rem * 16 + oc] = w0[i]; return; }
    i -= 144;
    if (i < 4608) { pack_one(w1, w1p, 32, 16, 16, 144, 9, 1, i); return; }
    i -= 4608;
    if (i < 18432) { pack_one(w2, w2p, 64, 32, 32, 288, 9, 1, i); return; }
    i -= 18432;
    if (i < 73728) { pack_one(w3, w3p, 128, 64, 32, 576, 9, 1, i); return; }
    i -= 73728;
    if (i < 65536) { pack_one(Wihf, wfp, 512, 128, 32, 128, 1, 0, i); return; }
    i -= 65536;
    if (i < 65536) { pack_one(Wihb, wbp, 512, 128, 32, 128, 1, 0, i); return; }
    i -= 65536;
    if (i < 65536) { pack_whh_one(Whhf, whhfp, i); return; }
    i -= 65536;
    if (i < 65536) { pack_whh_one(Whhb, whhbp, i); return; }
}

__global__ void pack_wf16(const float* __restrict__ src, __half* __restrict__ dst,
                          int OC, int IC, int KS,
                          int oc_str, int ic_str, int k_str, int total) {
    int i = blockIdx.x * 256 + threadIdx.x;
    if (i >= total) return;
    pack_one(src, dst, OC, IC, KS, oc_str, ic_str, k_str, i);
}

// ---- conv0: 1->16 ch, VALU, NHWC f16 out (uint4-packed stores) --------------------
__global__ __launch_bounds__(256) void conv0_k(const float* __restrict__ in,
                                               const float* __restrict__ wT,
                                               const float* __restrict__ bias,
                                               __half* __restrict__ out) {
    __shared__ float wsm[9][16];
    __shared__ float bs[16];
    int tid = threadIdx.x;
    if (tid < 144) wsm[tid / 16][tid % 16] = wT[tid];
    if (tid < 16) bs[tid] = bias[tid];
    __syncthreads();
    int gid = blockIdx.x * 256 + tid;
    int ow = gid % 27;
    int t = (gid / 27) % 256;
    int bf = gid / (27 * 256);
    float acc[16];
#pragma unroll
    for (int o = 0; o < 16; o++) acc[o] = bs[o];
    int iw0 = ow * 3 - 1;
#pragma unroll
    for (int kh = 0; kh < 3; kh++) {
        int tt = t + kh - 1;
        if ((unsigned)tt >= 256u) continue;
        const float* ip = in + ((long)bf * 256 + tt) * 81;
#pragma unroll
        for (int kw = 0; kw < 3; kw++) {
            int iw = iw0 + kw;
            if ((unsigned)iw >= 81u) continue;
            float x = ip[iw];
#pragma unroll
            for (int o = 0; o < 16; o++) acc[o] += x * wsm[kh * 3 + kw][o];
        }
    }
    union OU { uint4 u; __half2 h2[4]; } o0, o1;
#pragma unroll
    for (int o = 0; o < 4; o++)
        o0.h2[o] = __floats2half2_rn(fmaxf(acc[2 * o], 0.f), fmaxf(acc[2 * o + 1], 0.f));
#pragma unroll
    for (int o = 0; o < 4; o++)
        o1.h2[o] = __floats2half2_rn(fmaxf(acc[8 + 2 * o], 0.f), fmaxf(acc[9 + 2 * o], 0.f));
    uint4* op = (uint4*)(out + (long)gid * 16);
    op[0] = o0.u;
    op[1] = o1.u;
}

// ---- MFMA implicit-GEMM conv: NHWC f16 in/out -------------------------------------
template<int IC, int OC, int WIN, int WOUT, int KS>
__global__ __launch_bounds__(256) void convM_k(const __half* __restrict__ in,
                                               const __half* __restrict__ wp,
                                               const float* __restrict__ bias,
                                               __half* __restrict__ out) {
    constexpr int NT = OC / 16;
    constexpr int CPK = IC / KS;
    constexpr int NCHUNK = 9 * CPK;
    constexpr int GRP = KS / 4;
    int tid = threadIdx.x;
    int lane = tid & 63;
    int wv = tid >> 6;
    int l15 = lane & 15;
    int g = lane >> 4;
    int m = blockIdx.x * 64 + wv * 16 + l15;
    int ow = m % WOUT;
    int t = (m / WOUT) % 256;
    int bf = m / (WOUT * 256);

    f4_t acc[NT];
#pragma unroll
    for (int nt = 0; nt < NT; nt++)
#pragma unroll
        for (int r = 0; r < 4; r++) acc[nt][r] = 0.f;

#pragma unroll
    for (int chunk = 0; chunk < NCHUNK; chunk++) {
        int khw = chunk / CPK, cc = chunk % CPK;
        int kh = khw / 3;
        int kw = khw - kh * 3;
        int tt = t + kh - 1;
        int iw = ow * 3 + kw - 1;
        bool ok = ((unsigned)tt < 256u) && ((unsigned)iw < (unsigned)WIN);
        long aoff = ok ? (((long)(bf * 256 + tt) * WIN + iw) * IC + cc * KS + g * GRP) : 0;
        if constexpr (KS == 32) {
            H8 af;
            af.u = *(const uint4*)(in + aoff);
            if (!ok) af.u = make_uint4(0u, 0u, 0u, 0u);
#pragma unroll
            for (int nt = 0; nt < NT; nt++) {
                H8 bf8;
                bf8.u = *(const uint4*)(wp + ((long)(chunk * 4 + g) * OC + nt * 16 + l15) * GRP);
                acc[nt] = __builtin_amdgcn_mfma_f32_16x16x32_f16(af.v, bf8.v, acc[nt], 0, 0, 0);
            }
        } else {
            H4 af;
            af.u = *(const uint2*)(in + aoff);
            if (!ok) af.u = make_uint2(0u, 0u);
#pragma unroll
            for (int nt = 0; nt < NT; nt++) {
                H4 bf4;
                bf4.u = *(const uint2*)(wp + ((long)(chunk * 4 + g) * OC + nt * 16 + l15) * GRP);
                acc[nt] = __builtin_amdgcn_mfma_f32_16x16x16f16(af.v, bf4.v, acc[nt], 0, 0, 0);
            }
        }
    }
    int orow = blockIdx.x * 64 + wv * 16 + g * 4;
#pragma unroll
    for (int nt = 0; nt < NT; nt++) {
        int oc = nt * 16 + l15;
        float b = bias[oc];
#pragma unroll
        for (int r = 0; r < 4; r++) {
            float v = fmaxf(acc[nt][r] + b, 0.f);
            out[(long)(orow + r) * OC + oc] = __float2half(v);
        }
    }
}

// ---- gates MFMA GEMM, TRANSPOSED output G'[(b*512+gate)*256 + tidx] ---------------
// fwd: tidx = t ; bwd: tidx = 255 - t (so lstm always reads ascending tidx).
// A-frags (X rows) hoisted and held in registers: X read ONCE per block (was 4x via
// blockIdx.y). Loop ng over the 4 column groups, reusing the LDS staging buffer.
// Output staged in LDS (reversal folded in) and written COALESCED (256B runs).
__global__ __launch_bounds__(256) void gates_k(const __half* __restrict__ X,
                                               const __half* __restrict__ wpf,
                                               const __half* __restrict__ wpb,
                                               const float* __restrict__ bf1,
                                               const float* __restrict__ bf2,
                                               const float* __restrict__ bb1,
                                               const float* __restrict__ bb2,
                                               __half* __restrict__ Gf,
                                               __half* __restrict__ Gb) {
    int dir = blockIdx.z;
    const __half* wp = dir ? wpb : wpf;
    const float* b1 = dir ? bb1 : bf1;
    const float* b2 = dir ? bb2 : bf2;
    __half* G = dir ? Gb : Gf;
    int tid = threadIdx.x;
    int lane = tid & 63;
    int wv = tid >> 6;
    int l15 = lane & 15;
    int g = lane >> 4;
    int bx = blockIdx.x;
    int b = bx >> 1;                 // seq
    int t0 = (bx & 1) * 128;         // t-half of this block
    long r0 = (long)bx * 128 + wv * 32;

    __shared__ __align__(16) __half sh2[128][136];  // [col][t], +8 pad vs bank aliasing

    // hoisted A-frags: all 4 k-chunks for both row-tiles (X read once)
    H8 a0c[4], a1c[4];
#pragma unroll
    for (int chunk = 0; chunk < 4; chunk++) {
        a0c[chunk].u = *(const uint4*)(X + (r0 + l15) * 128 + chunk * 32 + g * 8);
        a1c[chunk].u = *(const uint4*)(X + (r0 + 16 + l15) * 128 + chunk * 32 + g * 8);
    }

    int ts_start = dir ? 128 - t0 : t0;
    int tbw = wv * 32 + g * 4;

    for (int ng = 0; ng < 4; ng++) {
        int n0 = ng * 128;

        f4_t acc[2][8];
#pragma unroll
        for (int s = 0; s < 2; s++)
#pragma unroll
            for (int nt = 0; nt < 8; nt++)
#pragma unroll
                for (int r = 0; r < 4; r++) acc[s][nt][r] = 0.f;

#pragma unroll
        for (int chunk = 0; chunk < 4; chunk++) {
#pragma unroll
            for (int nt = 0; nt < 8; nt++) {
                H8 bw;
                bw.u = *(const uint4*)(wp + ((long)(chunk * 4 + g) * 512 + n0 + nt * 16 + l15) * 8);
                acc[0][nt] = __builtin_amdgcn_mfma_f32_16x16x32_f16(a0c[chunk].v, bw.v, acc[0][nt], 0, 0, 0);
                acc[1][nt] = __builtin_amdgcn_mfma_f32_16x16x32_f16(a1c[chunk].v, bw.v, acc[1][nt], 0, 0, 0);
            }
        }

        // stage: sh2[col_local][t_local] (bwd: t reversed within the 128-tile)
#pragma unroll
        for (int nt = 0; nt < 8; nt++) {
            int coll = nt * 16 + l15;
            int col = n0 + coll;
            float bias = b1[col] + b2[col];
#pragma unroll
            for (int s = 0; s < 2; s++) {
                int tbl = tbw + s * 16;
                U2H4 pk;
                if (!dir) {
#pragma unroll
                    for (int r = 0; r < 4; r++) pk.h[r] = __float2half(acc[s][nt][r] + bias);
                    *(uint2*)&sh2[coll][tbl] = pk.u;
                } else {
#pragma unroll
                    for (int r = 0; r < 4; r++) pk.h[3 - r] = __float2half(acc[s][nt][r] + bias);
                    *(uint2*)&sh2[coll][124 - tbl] = pk.u;
                }
            }
        }
        __syncthreads();

        // coalesced write-out: per gate-row 256B contiguous (16 lanes x 16B)
#pragma unroll
        for (int cc = 0; cc < 8; cc++) {
            int idx = cc * 256 + tid;
            int coll = idx >> 4;
            int ch = idx & 15;
            uint4 v = *(const uint4*)&sh2[coll][ch * 8];
            *(uint4*)(G + ((long)(b * 512 + n0 + coll)) * 256 + ts_start + ch * 8) = v;
        }
        __syncthreads();   // staging reads done before next group's overwrite
    }
}

// ---- LSTM recurrence: 256 blocks x 1024 thr (16 waves), 1 gate value per lane -----
// (unchanged — parked at ~183us; per-step serial skeleton is the floor)
__global__ __launch_bounds__(1024, 4) void lstm_k(const __half* __restrict__ Gf,
                                                  const __half* __restrict__ Gb,
                                                  const __half* __restrict__ whhfp,
                                                  const __half* __restrict__ whhbp,
                                                  __half* __restrict__ flat) {
    int bid = blockIdx.x;
    int dir = bid >> 7;
    int b0 = (bid & 127) * 2;
    const __half* G = dir ? Gb : Gf;
    const __half* wp = dir ? whhbp : whhfp;
    int tid = threadIdx.x;
    int w = tid >> 6;            // wave 0..15
    int lane = tid & 63;
    int l15 = lane & 15;
    int g2 = lane >> 4;          // class: 0=i, 1=f, 2=g, 3=o
    int chn = l15 >> 3;          // seq within block
    int u8 = l15 & 7;            // unit within wave's 8
    int unit = w * 8 + u8;       // 0..127
    int tsel = (u8 >> 2) & 1;
    int du = u8 & 3;

    // A-frags: 2 tiles x 4 k-chunks = 32 VGPRs/lane
    H8 afr[2][4];
#pragma unroll
    for (int t = 0; t < 2; t++) {
        int prow = (w * 2 + t) * 16 + l15;
#pragma unroll
        for (int c = 0; c < 4; c++)
            afr[t][c].u = *(const uint4*)(wp + ((long)((c * 4 + g2) * 512 + prow)) * 8);
    }

    __shared__ __align__(16) __half hbuf[2][2][128];
    if (tid < 256) hbuf[0][tid >> 7][tid & 127] = __float2half(0.f);
    __syncthreads();

    // this lane's single gate row in transposed G
    const __half* gb0 = G + (((long)(b0 + chn) * 512) + g2 * 128 + unit) * 256;

    float cst = 0.f;                         // cell state, valid on g2==1 lanes
    float ma = (g2 == 2) ? 2.f : 1.f;        // tanh(z) = 2*sigmoid(2z)-1 on g-lanes
    float mb = ma;
    float cb = (g2 == 2) ? -1.f : 0.f;
    const f4_t zero4 = {0.f, 0.f, 0.f, 0.f};

    H8 gc, gn;
    gc.u = *(const uint4*)(gb0);
    long fbase = (long)(b0 + chn) * 65536 + dir * 128 + unit;

    for (int to = 0; to < 32; to++) {
        if (to < 31) gn.u = *(const uint4*)(gb0 + (to + 1) * 8);
#pragma unroll
        for (int ti = 0; ti < 8; ti++) {
            int s = to * 8 + ti;
            int p = s & 1;
            H8 bfr[4];
#pragma unroll
            for (int c = 0; c < 4; c++)
                bfr[c].u = *(const uint4*)(&hbuf[p][chn][c * 32 + g2 * 8]);

            f4_t acc[2];
#pragma unroll
            for (int t = 0; t < 2; t++)
                acc[t] = __builtin_amdgcn_mfma_f32_16x16x32_f16(afr[t][0].v, bfr[0].v,
                                                                zero4, 0, 0, 0);
#pragma unroll
            for (int c = 1; c < 4; c++)
#pragma unroll
                for (int t = 0; t < 2; t++)
                    acc[t] = __builtin_amdgcn_mfma_f32_16x16x32_f16(afr[t][c].v, bfr[c].v,
                                                                    acc[t], 0, 0, 0);
            // select acc[tsel][du]
            f4_t at;
#pragma unroll
            for (int e = 0; e < 4; e++) at[e] = tsel ? acc[1][e] : acc[0][e];
            float lo = (du & 1) ? at[1] : at[0];
            float hi = (du & 1) ? at[3] : at[2];
            float ev = (du & 2) ? hi : lo;

            float z = ev + (float)gc.v[ti];
            float a = sigmoidf_(ma * z) * mb + cb;   // i,f,o: sigmoid; g: tanh

            float x1 = xswap32(a, lane);             // i<->g, f<->o (VALU permlane)
            float pi = a * x1;                       // on g2=0: sig(i)*tanh(g)
            float x2 = __shfl_xor(pi, 16, 64);       // g2=1 <- g2=0
            float cn = a * cst + x2;                 // on g2=1: sig(f)*c + pi
            cst = cn;
            float tc = tanhf_(cn);
            float x3 = xswap32(tc, lane);            // g2=3 <- g2=1 (VALU permlane)
            float h = a * x3;                        // on g2=3: sig(o)*tanh(c')

            if (g2 == 3) {
                __half hh = __float2half(h);
                int ts = dir ? (255 - s) : s;
                hbuf[p ^ 1][chn][unit] = hh;
                flat[fbase + (long)ts * 256] = hh;
            }
            wg_barrier_lds();
        }
        gc = gn;
    }
}

// ---- FC1 MFMA split-K: z[256][128] += flat16 @ fc1_w16^T --------------------------
__global__ __launch_bounds__(256) void fc1m_k(const __half* __restrict__ flat,
                                              const __half* __restrict__ wp,
                                              float* __restrict__ z) {
    int tid = threadIdx.x;
    int lane = tid & 63;
    int wv = tid >> 6;
    int l15 = lane & 15;
    int g = lane >> 4;
    int m0 = blockIdx.x * 64 + wv * 16;
    long k0 = (long)blockIdx.y * 1024;

    f4_t acc[8];
#pragma unroll
    for (int nt = 0; nt < 8; nt++)
#pragma unroll
        for (int r = 0; r < 4; r++) acc[nt][r] = 0.f;

    for (int c = 0; c < 32; c++) {
        long chunk = (k0 >> 5) + c;
        H8 af;
        af.u = *(const uint4*)(flat + (long)(m0 + l15) * 65536 + k0 + c * 32 + g * 8);
#pragma unroll
        for (int nt = 0; nt < 8; nt++) {
            H8 bw;
            bw.u = *(const uint4*)(wp + ((chunk * 4 + g) * 128 + nt * 16 + l15) * 8);
            acc[nt] = __builtin_amdgcn_mfma_f32_16x16x32_f16(af.v, bw.v, acc[nt], 0, 0, 0);
        }
    }
#pragma unroll
    for (int nt = 0; nt < 8; nt++)
#pragma unroll
        for (int r = 0; r < 4; r++)
            atomicAdd(&z[(m0 + g * 4 + r) * 128 + nt * 16 + l15], acc[nt][r]);
}

__global__ void zero_k(float* __restrict__ p, int n) {
    int i = blockIdx.x * 256 + threadIdx.x;
    if (i < n) p[i] = 0.f;
}

// ---- head -------------------------------------------------------------------------
__global__ __launch_bounds__(256) void head_k(const float* __restrict__ z,
                                              const float* __restrict__ b1,
                                              const float* __restrict__ fsw,
                                              const float* __restrict__ fsb,
                                              float* __restrict__ out) {
    __shared__ float sf[256];
    int r = threadIdx.x;
    float acc = fsb[0];
#pragma unroll
    for (int j4 = 0; j4 < 32; j4++) {
        float4 zv = *(const float4*)&z[r * 128 + j4 * 4];
        float4 bv = *(const float4*)&b1[j4 * 4];
        float4 wv = *(const float4*)&fsw[j4 * 4];
        acc += fmaxf(zv.x + bv.x, 0.f) * wv.x;
        acc += fmaxf(zv.y + bv.y, 0.f) * wv.y;
        acc += fmaxf(zv.z + bv.z, 0.f) * wv.z;
        acc += fmaxf(zv.w + bv.w, 0.f) * wv.w;
    }
    float val = sigmoidf_(acc) * 4.f + 1.f;
    out[16 + r] = val;
    sf[r] = val;
    __syncthreads();
    if (r < 16) {
        float m = 0.f;
#pragma unroll
        for (int f = 0; f < 16; f++) m += sf[r * 16 + f];
        out[r] = m * (1.f / 16.f);
    }
}

extern "C" void kernel_launch(void* const* d_in, const int* in_sizes, int n_in,
                              void* d_out, int out_size, void* d_ws, size_t ws_size,
                              hipStream_t stream) {
    const float* audio = (const float*)d_in[0];
    const float* w0 = (const float*)d_in[2];
    const float* b0 = (const float*)d_in[3];
    const float* w1 = (const float*)d_in[4];
    const float* b1 = (const float*)d_in[5];
    const float* w2 = (const float*)d_in[6];
    const float* b2 = (const float*)d_in[7];
    const float* w3 = (const float*)d_in[8];
    const float* b3 = (const float*)d_in[9];
    const float* Wih_f = (const float*)d_in[10];
    const float* Whh_f = (const float*)d_in[11];
    const float* bih_f = (const float*)d_in[12];
    const float* bhh_f = (const float*)d_in[13];
    const float* Wih_b = (const float*)d_in[14];
    const float* Whh_b = (const float*)d_in[15];
    const float* bih_b = (const float*)d_in[16];
    const float* bhh_b = (const float*)d_in[17];
    const float* fc1_w = (const float*)d_in[18];
    const float* fc1_b = (const float*)d_in[19];
    const float* fs_w = (const float*)d_in[20];
    const float* fs_b = (const float*)d_in[21];
    float* out = (float*)d_out;

    char* ws = (char*)d_ws;
    // lifetimes: out1 dies before Gf; out0 dies before flat16; Gf/Gb die before fc1p
    __half* Gf    = (__half*)(ws);                    // 67.1 MB (transposed layout)
    __half* out1  = (__half*)(ws);                    // 37.7 MB (pre-Gf)
    __half* fc1p  = (__half*)(ws);                    // 16.8 MB (post-lstm, in Gf)
    __half* Gb    = (__half*)(ws + 67108864);         // 67.1 MB
    __half* flat16= (__half*)(ws + 134217728);        // 33.6 MB
    __half* out0  = (__half*)(ws + 134217728);        // 56.6 MB (pre-flat16)
    __half* X     = (__half*)(ws + 201326592);        // 16.8 MB
    __half* out2  = (__half*)(ws + 218103808);        // 25.2 MB
    char* rd = ws + 243269632;
    float*  w0t   = (float*)(rd);
    __half* w1p   = (__half*)(rd + 1024);
    __half* w2p   = (__half*)(rd + 10240);
    __half* w3p   = (__half*)(rd + 47104);
    __half* wfp   = (__half*)(rd + 194560);
    __half* wbp   = (__half*)(rd + 325632);
    __half* whhfp = (__half*)(rd + 456704);
    __half* whhbp = (__half*)(rd + 587776);
    float*  zbuf  = (float*)(rd + 718848);

    // fused weight prep (1 launch)
    prep_k<<<1403, 256, 0, stream>>>(w0, w1, w2, w3, Wih_f, Wih_b, Whh_f, Whh_b,
                                     w0t, w1p, w2p, w3p, wfp, wbp, whhfp, whhbp);

    // conv chain (NHWC f16)
    conv0_k<<<6912, 256, 0, stream>>>(audio, w0t, b0, out0);
    convM_k<16, 32, 27, 9, 16><<<9216, 256, 0, stream>>>(out0, w1p, b1, out1);
    convM_k<32, 64, 9, 3, 32><<<3072, 256, 0, stream>>>(out1, w2p, b2, out2);
    convM_k<64, 128, 3, 1, 32><<<1024, 256, 0, stream>>>(out2, w3p, b3, X);

    // gates: X read once per block, all 4 col-groups looped in-block
    gates_k<<<dim3(512, 1, 2), 256, 0, stream>>>(X, wfp, wbp, bih_f, bhh_f,
                                                 bih_b, bhh_b, Gf, Gb);

    // recurrence (16 waves, 1 gate value/lane, permlane stitches, 1 lgkm barrier/step)
    lstm_k<<<256, 1024, 0, stream>>>(Gf, Gb, whhfp, whhbp, flat16);

    // FC head: pack fc1_w (into dead Gf region), split-K MFMA, head
    pack_wf16<<<32768, 256, 0, stream>>>(fc1_w, fc1p, 128, 65536, 32, 65536, 1, 0, 8388608);
    zero_k<<<128, 256, 0, stream>>>(zbuf, 256 * 128);
    fc1m_k<<<dim3(4, 64), 256, 0, stream>>>(flat16, fc1p, zbuf);
    head_k<<<1, 256, 0, stream>>>(zbuf, fc1_b, fs_w, fs_b, out);
}

// Round 9
// 508.523 us; speedup vs baseline: 1.1740x; 1.0588x over previous
//
#include <hip/hip_runtime.h>
#include <hip/hip_fp16.h>

#define BF 256
#define TSTEPS 256

typedef _Float16 h8_t __attribute__((ext_vector_type(8)));
typedef _Float16 h4_t __attribute__((ext_vector_type(4)));
typedef float f4_t __attribute__((ext_vector_type(4)));

union H8 { uint4 u; h8_t v; };
union H4 { uint2 u; h4_t v; };
union U2H4 { uint2 u; __half h[4]; };

// fast sigmoid/tanh: v_exp + v_rcp (error << f16 storage quantization of h)
static __device__ __forceinline__ float sigmoidf_(float x) {
    return __builtin_amdgcn_rcpf(1.f + __expf(-x));
}
static __device__ __forceinline__ float tanhf_(float x) {
    return 1.f - 2.f * __builtin_amdgcn_rcpf(__expf(2.f * x) + 1.f);
}

// xor-32 lane exchange on the VALU (v_permlane32_swap_b32) instead of the LDS
// crossbar (ds_swizzle). Bit-exact vs __shfl_xor(x,32).
static __device__ __forceinline__ float xswap32(float x, int lane) {
    typedef unsigned uv2 __attribute__((ext_vector_type(2)));
    unsigned xu = __float_as_uint(x);
    uv2 r = __builtin_amdgcn_permlane32_swap(xu, xu, false, false);
    return __uint_as_float((lane & 32) ? r[0] : r[1]);
}

// LDS-only workgroup barrier: drains lgkmcnt (ds ops) but leaves vmcnt
// (global stores of h / X prefetch loads) in flight across the barrier.
static __device__ __forceinline__ void wg_barrier_lds() {
    __builtin_amdgcn_sched_barrier(0);
    asm volatile("s_waitcnt lgkmcnt(0)" ::: "memory");
    __builtin_amdgcn_s_barrier();
    __builtin_amdgcn_sched_barrier(0);
}

// ---- pack helper: f16 MFMA operand layout -----------------------------------------
static __device__ __forceinline__ void pack_one(const float* __restrict__ src,
                                                __half* __restrict__ dst,
                                                int OC, int IC, int KS,
                                                int oc_str, int ic_str, int k_str, int i) {
    int grp = KS / 4;
    int j = i % grp;
    int oc = (i / grp) % OC;
    int g = (i / (grp * OC)) & 3;
    int chunk = i / (grp * OC * 4);
    int CPK = IC / KS;
    int cc = chunk % CPK;
    int khw = chunk / CPK;
    int ic = cc * KS + g * grp + j;
    dst[i] = __float2half(src[(long)oc * oc_str + (long)ic * ic_str + khw * k_str]);
}

// Whh/Wih pack with class-interleaved row permutation: packed row prow = T*16+cls*4+du
// maps to original row cls*128 + T*4 + du. A 16-row MFMA tile then holds
// 4 classes x 4 units; wave w (2 tiles) covers units [8w,8w+8) x all 4 classes.
static __device__ __forceinline__ void pack_whh_one(const float* __restrict__ src,
                                                    __half* __restrict__ dst, int i) {
    int j = i & 7;
    int prow = (i >> 3) & 511;
    int cg = i >> 12;            // chunk*4 + g
    int g = cg & 3, chunk = cg >> 2;
    int t = prow >> 4, rr = prow & 15;
    int cls = rr >> 2, du = rr & 3;
    int orig = cls * 128 + t * 4 + du;
    int ic = chunk * 32 + g * 8 + j;
    dst[i] = __float2half(src[orig * 128 + ic]);
}

// ---- fused weight prep ------------------------------------------------------------
// NOTE: Wih is now packed class-interleaved (pack_whh_one) since it is consumed as
// the A-operand inside the fused lstm kernel, with the same tile map as Whh.
__global__ __launch_bounds__(256) void prep_k(
        const float* __restrict__ w0, const float* __restrict__ w1,
        const float* __restrict__ w2, const float* __restrict__ w3,
        const float* __restrict__ Wihf, const float* __restrict__ Wihb,
        const float* __restrict__ Whhf, const float* __restrict__ Whhb,
        float* __restrict__ w0t, __half* __restrict__ w1p,
        __half* __restrict__ w2p, __half* __restrict__ w3p,
        __half* __restrict__ wfp, __half* __restrict__ wbp,
        __half* __restrict__ whhfp, __half* __restrict__ whhbp) {
    int i = blockIdx.x * 256 + threadIdx.x;
    if (i < 144) { int oc = i / 9, rem = i % 9; w0t[rem * 16 + oc] = w0[i]; return; }
    i -= 144;
    if (i < 4608) { pack_one(w1, w1p, 32, 16, 16, 144, 9, 1, i); return; }
    i -= 4608;
    if (i < 18432) { pack_one(w2, w2p, 64, 32, 32, 288, 9, 1, i); return; }
    i -= 18432;
    if (i < 73728) { pack_one(w3, w3p, 128, 64, 32, 576, 9, 1, i); return; }
    i -= 73728;
    if (i < 65536) { pack_whh_one(Wihf, wfp, i); return; }
    i -= 65536;
    if (i < 65536) { pack_whh_one(Wihb, wbp, i); return; }
    i -= 65536;
    if (i < 65536) { pack_whh_one(Whhf, whhfp, i); return; }
    i -= 65536;
    if (i < 65536) { pack_whh_one(Whhb, whhbp, i); return; }
}

__global__ void pack_wf16(const float* __restrict__ src, __half* __restrict__ dst,
                          int OC, int IC, int KS,
                          int oc_str, int ic_str, int k_str, int total) {
    int i = blockIdx.x * 256 + threadIdx.x;
    if (i >= total) return;
    pack_one(src, dst, OC, IC, KS, oc_str, ic_str, k_str, i);
}

// ---- conv0: 1->16 ch, VALU, NHWC f16 out (uint4-packed stores) --------------------
__global__ __launch_bounds__(256) void conv0_k(const float* __restrict__ in,
                                               const float* __restrict__ wT,
                                               const float* __restrict__ bias,
                                               __half* __restrict__ out) {
    __shared__ float wsm[9][16];
    __shared__ float bs[16];
    int tid = threadIdx.x;
    if (tid < 144) wsm[tid / 16][tid % 16] = wT[tid];
    if (tid < 16) bs[tid] = bias[tid];
    __syncthreads();
    int gid = blockIdx.x * 256 + tid;
    int ow = gid % 27;
    int t = (gid / 27) % 256;
    int bf = gid / (27 * 256);
    float acc[16];
#pragma unroll
    for (int o = 0; o < 16; o++) acc[o] = bs[o];
    int iw0 = ow * 3 - 1;
#pragma unroll
    for (int kh = 0; kh < 3; kh++) {
        int tt = t + kh - 1;
        if ((unsigned)tt >= 256u) continue;
        const float* ip = in + ((long)bf * 256 + tt) * 81;
#pragma unroll
        for (int kw = 0; kw < 3; kw++) {
            int iw = iw0 + kw;
            if ((unsigned)iw >= 81u) continue;
            float x = ip[iw];
#pragma unroll
            for (int o = 0; o < 16; o++) acc[o] += x * wsm[kh * 3 + kw][o];
        }
    }
    union OU { uint4 u; __half2 h2[4]; } o0, o1;
#pragma unroll
    for (int o = 0; o < 4; o++)
        o0.h2[o] = __floats2half2_rn(fmaxf(acc[2 * o], 0.f), fmaxf(acc[2 * o + 1], 0.f));
#pragma unroll
    for (int o = 0; o < 4; o++)
        o1.h2[o] = __floats2half2_rn(fmaxf(acc[8 + 2 * o], 0.f), fmaxf(acc[9 + 2 * o], 0.f));
    uint4* op = (uint4*)(out + (long)gid * 16);
    op[0] = o0.u;
    op[1] = o1.u;
}

// ---- MFMA implicit-GEMM conv: NHWC f16 in/out -------------------------------------
template<int IC, int OC, int WIN, int WOUT, int KS>
__global__ __launch_bounds__(256) void convM_k(const __half* __restrict__ in,
                                               const __half* __restrict__ wp,
                                               const float* __restrict__ bias,
                                               __half* __restrict__ out) {
    constexpr int NT = OC / 16;
    constexpr int CPK = IC / KS;
    constexpr int NCHUNK = 9 * CPK;
    constexpr int GRP = KS / 4;
    int tid = threadIdx.x;
    int lane = tid & 63;
    int wv = tid >> 6;
    int l15 = lane & 15;
    int g = lane >> 4;
    int m = blockIdx.x * 64 + wv * 16 + l15;
    int ow = m % WOUT;
    int t = (m / WOUT) % 256;
    int bf = m / (WOUT * 256);

    f4_t acc[NT];
#pragma unroll
    for (int nt = 0; nt < NT; nt++)
#pragma unroll
        for (int r = 0; r < 4; r++) acc[nt][r] = 0.f;

#pragma unroll
    for (int chunk = 0; chunk < NCHUNK; chunk++) {
        int khw = chunk / CPK, cc = chunk % CPK;
        int kh = khw / 3;
        int kw = khw - kh * 3;
        int tt = t + kh - 1;
        int iw = ow * 3 + kw - 1;
        bool ok = ((unsigned)tt < 256u) && ((unsigned)iw < (unsigned)WIN);
        long aoff = ok ? (((long)(bf * 256 + tt) * WIN + iw) * IC + cc * KS + g * GRP) : 0;
        if constexpr (KS == 32) {
            H8 af;
            af.u = *(const uint4*)(in + aoff);
            if (!ok) af.u = make_uint4(0u, 0u, 0u, 0u);
#pragma unroll
            for (int nt = 0; nt < NT; nt++) {
                H8 bf8;
                bf8.u = *(const uint4*)(wp + ((long)(chunk * 4 + g) * OC + nt * 16 + l15) * GRP);
                acc[nt] = __builtin_amdgcn_mfma_f32_16x16x32_f16(af.v, bf8.v, acc[nt], 0, 0, 0);
            }
        } else {
            H4 af;
            af.u = *(const uint2*)(in + aoff);
            if (!ok) af.u = make_uint2(0u, 0u);
#pragma unroll
            for (int nt = 0; nt < NT; nt++) {
                H4 bf4;
                bf4.u = *(const uint2*)(wp + ((long)(chunk * 4 + g) * OC + nt * 16 + l15) * GRP);
                acc[nt] = __builtin_amdgcn_mfma_f32_16x16x16f16(af.v, bf4.v, acc[nt], 0, 0, 0);
            }
        }
    }
    int orow = blockIdx.x * 64 + wv * 16 + g * 4;
#pragma unroll
    for (int nt = 0; nt < NT; nt++) {
        int oc = nt * 16 + l15;
        float b = bias[oc];
#pragma unroll
        for (int r = 0; r < 4; r++) {
            float v = fmaxf(acc[nt][r] + b, 0.f);
            out[(long)(orow + r) * OC + oc] = __float2half(v);
        }
    }
}

// ---- FUSED LSTM: gates (Wih@x) computed in-kernel, 8-step windows -----------------
// Structure unchanged from the 183us kernel: 256 blocks x 16 waves, wave w owns
// units [8w,8w+8) x 4 classes, 2 seqs/block packed in MFMA cols, 1 barrier/step.
// NEW: instead of reading pre-computed G from HBM, each wave computes its OWN
// 32 gate-rows' z_ih for the next 8-step window with 8 extra MFMAs (cols = 2 seqs
// x 8 t, fully packed -> only +1 MFMA/step). The redistribution (producer lane
// holds rows g2*4+r / col l15; consumer wants its unit's 8 t-values) is a purely
// INTRA-WAVE LDS round-trip (per-wave scratch, no barrier). Window work sits
// outside the per-step serial chain. Deletes gates_k + 268MB of G traffic.
// Bit-exact: same K-chunk order as gates_k; A/B swap preserves each dot product's
// product set and k-reduction tree; f16 rounding point identical (bias is zero).
__global__ __launch_bounds__(1024, 4) void lstm_k(const __half* __restrict__ X,
                                                  const __half* __restrict__ wihfp,
                                                  const __half* __restrict__ wihbp,
                                                  const __half* __restrict__ whhfp,
                                                  const __half* __restrict__ whhbp,
                                                  const float* __restrict__ bihf,
                                                  const float* __restrict__ bhhf,
                                                  const float* __restrict__ bihb,
                                                  const float* __restrict__ bhhb,
                                                  __half* __restrict__ flat) {
    int bid = blockIdx.x;
    int dir = bid >> 7;
    int b0 = (bid & 127) * 2;
    const __half* wp  = dir ? whhbp : whhfp;
    const __half* wip = dir ? wihbp : wihfp;
    const float* bA = dir ? bihb : bihf;
    const float* bB = dir ? bhhb : bhhf;
    int tid = threadIdx.x;
    int w = tid >> 6;            // wave 0..15
    int lane = tid & 63;
    int l15 = lane & 15;
    int g2 = lane >> 4;          // class: 0=i, 1=f, 2=g, 3=o
    int chn = l15 >> 3;          // seq within block
    int u8 = l15 & 7;            // unit within wave's 8
    int unit = w * 8 + u8;       // 0..127
    int tsel = (u8 >> 2) & 1;
    int du = u8 & 3;
    int tw = l15 & 7;            // producer col timestep-within-window

    // A-frags: Whh + Wih, each 2 tiles x 4 k-chunks
    H8 afr[2][4], aih[2][4];
#pragma unroll
    for (int t = 0; t < 2; t++) {
        int prow = (w * 2 + t) * 16 + l15;
#pragma unroll
        for (int c = 0; c < 4; c++) {
            afr[t][c].u = *(const uint4*)(wp  + ((long)((c * 4 + g2) * 512 + prow)) * 8);
            aih[t][c].u = *(const uint4*)(wip + ((long)((c * 4 + g2) * 512 + prow)) * 8);
        }
    }
    float cbias = bA[g2 * 128 + unit] + bB[g2 * 128 + unit];

    __shared__ __align__(16) __half hbuf[2][2][128];
    __shared__ __align__(16) __half zsc[16][32][16];   // per-wave z_ih scratch
    if (tid < 256) hbuf[0][tid >> 7][tid & 127] = __float2half(0.f);
    __syncthreads();

    const f4_t zero4 = {0.f, 0.f, 0.f, 0.f};
    float cst = 0.f;                         // cell state, valid on g2==1 lanes
    float ma = (g2 == 2) ? 2.f : 1.f;        // tanh(z) = 2*sigmoid(2z)-1 on g-lanes
    float mb = ma;
    float cb = (g2 == 2) ? -1.f : 0.f;
    long fbase = (long)(b0 + chn) * 65536 + dir * 128 + unit;
    long xrow = (long)(b0 + chn) * 256;

    H8 gc;
    // window producer: compute z_ih for 8-step window wnd, result -> gc (intra-wave)
    auto window = [&](int wnd) {
        int tp = dir ? (255 - (wnd * 8 + tw)) : (wnd * 8 + tw);
        const __half* xb = X + (xrow + tp) * 128 + g2 * 8;
        H8 bx0, bx1, bx2, bx3;
        bx0.u = *(const uint4*)(xb);
        bx1.u = *(const uint4*)(xb + 32);
        bx2.u = *(const uint4*)(xb + 64);
        bx3.u = *(const uint4*)(xb + 96);
        f4_t z0, z1;
        z0 = __builtin_amdgcn_mfma_f32_16x16x32_f16(aih[0][0].v, bx0.v, zero4, 0, 0, 0);
        z1 = __builtin_amdgcn_mfma_f32_16x16x32_f16(aih[1][0].v, bx0.v, zero4, 0, 0, 0);
        z0 = __builtin_amdgcn_mfma_f32_16x16x32_f16(aih[0][1].v, bx1.v, z0, 0, 0, 0);
        z1 = __builtin_amdgcn_mfma_f32_16x16x32_f16(aih[1][1].v, bx1.v, z1, 0, 0, 0);
        z0 = __builtin_amdgcn_mfma_f32_16x16x32_f16(aih[0][2].v, bx2.v, z0, 0, 0, 0);
        z1 = __builtin_amdgcn_mfma_f32_16x16x32_f16(aih[1][2].v, bx2.v, z1, 0, 0, 0);
        z0 = __builtin_amdgcn_mfma_f32_16x16x32_f16(aih[0][3].v, bx3.v, z0, 0, 0, 0);
        z1 = __builtin_amdgcn_mfma_f32_16x16x32_f16(aih[1][3].v, bx3.v, z1, 0, 0, 0);
        // producer lane holds rows g2*4+r (tile 0/1) for col l15 = chn*8 + tw
#pragma unroll
        for (int r = 0; r < 4; r++) {
            zsc[w][g2 * 4 + r][l15]      = __float2half(z0[r]);
            zsc[w][16 + g2 * 4 + r][l15] = __float2half(z1[r]);
        }
        // LDS ops are in-order per wave: this read sees the writes above.
        gc.u = *(const uint4*)&zsc[w][tsel * 16 + g2 * 4 + du][chn * 8];
    };
    window(0);

    for (int to = 0; to < 32; to++) {
#pragma unroll
        for (int ti = 0; ti < 8; ti++) {
            int s = to * 8 + ti;
            int p = s & 1;
            H8 bfr[4];
#pragma unroll
            for (int c = 0; c < 4; c++)
                bfr[c].u = *(const uint4*)(&hbuf[p][chn][c * 32 + g2 * 8]);

            f4_t acc[2];
#pragma unroll
            for (int t = 0; t < 2; t++)
                acc[t] = __builtin_amdgcn_mfma_f32_16x16x32_f16(afr[t][0].v, bfr[0].v,
                                                                zero4, 0, 0, 0);
#pragma unroll
            for (int c = 1; c < 4; c++)
#pragma unroll
                for (int t = 0; t < 2; t++)
                    acc[t] = __builtin_amdgcn_mfma_f32_16x16x32_f16(afr[t][c].v, bfr[c].v,
                                                                    acc[t], 0, 0, 0);
            // select acc[tsel][du]
            f4_t at;
#pragma unroll
            for (int e = 0; e < 4; e++) at[e] = tsel ? acc[1][e] : acc[0][e];
            float lo = (du & 1) ? at[1] : at[0];
            float hi = (du & 1) ? at[3] : at[2];
            float ev = (du & 2) ? hi : lo;

            float z = ev + (float)gc.v[ti] + cbias;
            float a = sigmoidf_(ma * z) * mb + cb;   // i,f,o: sigmoid; g: tanh

            float x1 = xswap32(a, lane);             // i<->g, f<->o (VALU permlane)
            float pi = a * x1;                       // on g2=0: sig(i)*tanh(g)
            float x2 = __shfl_xor(pi, 16, 64);       // g2=1 <- g2=0
            float cn = a * cst + x2;                 // on g2=1: sig(f)*c + pi
            cst = cn;
            float tc = tanhf_(cn);
            float x3 = xswap32(tc, lane);            // g2=3 <- g2=1 (VALU permlane)
            float h = a * x3;                        // on g2=3: sig(o)*tanh(c')

            if (g2 == 3) {
                __half hh = __float2half(h);
                int ts = dir ? (255 - s) : s;
                hbuf[p ^ 1][chn][unit] = hh;
                flat[fbase + (long)ts * 256] = hh;
            }
            wg_barrier_lds();
        }
        if (to < 31) window(to + 1);
    }
}

// ---- FC1 MFMA split-K: z[256][128] += flat16 @ fc1_w16^T --------------------------
__global__ __launch_bounds__(256) void fc1m_k(const __half* __restrict__ flat,
                                              const __half* __restrict__ wp,
                                              float* __restrict__ z) {
    int tid = threadIdx.x;
    int lane = tid & 63;
    int wv = tid >> 6;
    int l15 = lane & 15;
    int g = lane >> 4;
    int m0 = blockIdx.x * 64 + wv * 16;
    long k0 = (long)blockIdx.y * 1024;

    f4_t acc[8];
#pragma unroll
    for (int nt = 0; nt < 8; nt++)
#pragma unroll
        for (int r = 0; r < 4; r++) acc[nt][r] = 0.f;

    for (int c = 0; c < 32; c++) {
        long chunk = (k0 >> 5) + c;
        H8 af;
        af.u = *(const uint4*)(flat + (long)(m0 + l15) * 65536 + k0 + c * 32 + g * 8);
#pragma unroll
        for (int nt = 0; nt < 8; nt++) {
            H8 bw;
            bw.u = *(const uint4*)(wp + ((chunk * 4 + g) * 128 + nt * 16 + l15) * 8);
            acc[nt] = __builtin_amdgcn_mfma_f32_16x16x32_f16(af.v, bw.v, acc[nt], 0, 0, 0);
        }
    }
#pragma unroll
    for (int nt = 0; nt < 8; nt++)
#pragma unroll
        for (int r = 0; r < 4; r++)
            atomicAdd(&z[(m0 + g * 4 + r) * 128 + nt * 16 + l15], acc[nt][r]);
}

__global__ void zero_k(float* __restrict__ p, int n) {
    int i = blockIdx.x * 256 + threadIdx.x;
    if (i < n) p[i] = 0.f;
}

// ---- head -------------------------------------------------------------------------
__global__ __launch_bounds__(256) void head_k(const float* __restrict__ z,
                                              const float* __restrict__ b1,
                                              const float* __restrict__ fsw,
                                              const float* __restrict__ fsb,
                                              float* __restrict__ out) {
    __shared__ float sf[256];
    int r = threadIdx.x;
    float acc = fsb[0];
#pragma unroll
    for (int j4 = 0; j4 < 32; j4++) {
        float4 zv = *(const float4*)&z[r * 128 + j4 * 4];
        float4 bv = *(const float4*)&b1[j4 * 4];
        float4 wv = *(const float4*)&fsw[j4 * 4];
        acc += fmaxf(zv.x + bv.x, 0.f) * wv.x;
        acc += fmaxf(zv.y + bv.y, 0.f) * wv.y;
        acc += fmaxf(zv.z + bv.z, 0.f) * wv.z;
        acc += fmaxf(zv.w + bv.w, 0.f) * wv.w;
    }
    float val = sigmoidf_(acc) * 4.f + 1.f;
    out[16 + r] = val;
    sf[r] = val;
    __syncthreads();
    if (r < 16) {
        float m = 0.f;
#pragma unroll
        for (int f = 0; f < 16; f++) m += sf[r * 16 + f];
        out[r] = m * (1.f / 16.f);
    }
}

extern "C" void kernel_launch(void* const* d_in, const int* in_sizes, int n_in,
                              void* d_out, int out_size, void* d_ws, size_t ws_size,
                              hipStream_t stream) {
    const float* audio = (const float*)d_in[0];
    const float* w0 = (const float*)d_in[2];
    const float* b0 = (const float*)d_in[3];
    const float* w1 = (const float*)d_in[4];
    const float* b1 = (const float*)d_in[5];
    const float* w2 = (const float*)d_in[6];
    const float* b2 = (const float*)d_in[7];
    const float* w3 = (const float*)d_in[8];
    const float* b3 = (const float*)d_in[9];
    const float* Wih_f = (const float*)d_in[10];
    const float* Whh_f = (const float*)d_in[11];
    const float* bih_f = (const float*)d_in[12];
    const float* bhh_f = (const float*)d_in[13];
    const float* Wih_b = (const float*)d_in[14];
    const float* Whh_b = (const float*)d_in[15];
    const float* bih_b = (const float*)d_in[16];
    const float* bhh_b = (const float*)d_in[17];
    const float* fc1_w = (const float*)d_in[18];
    const float* fc1_b = (const float*)d_in[19];
    const float* fs_w = (const float*)d_in[20];
    const float* fs_b = (const float*)d_in[21];
    float* out = (float*)d_out;

    char* ws = (char*)d_ws;
    // lifetimes: out1 dies before fc1p; out0 dies before flat16
    __half* out1  = (__half*)(ws);                    // 37.7 MB
    __half* fc1p  = (__half*)(ws);                    // 16.8 MB (post-lstm)
    __half* flat16= (__half*)(ws + 134217728);        // 33.6 MB
    __half* out0  = (__half*)(ws + 134217728);        // 56.6 MB (pre-flat16)
    __half* X     = (__half*)(ws + 201326592);        // 16.8 MB
    __half* out2  = (__half*)(ws + 218103808);        // 25.2 MB
    char* rd = ws + 243269632;
    float*  w0t   = (float*)(rd);
    __half* w1p   = (__half*)(rd + 1024);
    __half* w2p   = (__half*)(rd + 10240);
    __half* w3p   = (__half*)(rd + 47104);
    __half* wfp   = (__half*)(rd + 194560);
    __half* wbp   = (__half*)(rd + 325632);
    __half* whhfp = (__half*)(rd + 456704);
    __half* whhbp = (__half*)(rd + 587776);
    float*  zbuf  = (float*)(rd + 718848);

    // fused weight prep (1 launch)
    prep_k<<<1403, 256, 0, stream>>>(w0, w1, w2, w3, Wih_f, Wih_b, Whh_f, Whh_b,
                                     w0t, w1p, w2p, w3p, wfp, wbp, whhfp, whhbp);

    // conv chain (NHWC f16)
    conv0_k<<<6912, 256, 0, stream>>>(audio, w0t, b0, out0);
    convM_k<16, 32, 27, 9, 16><<<9216, 256, 0, stream>>>(out0, w1p, b1, out1);
    convM_k<32, 64, 9, 3, 32><<<3072, 256, 0, stream>>>(out1, w2p, b2, out2);
    convM_k<64, 128, 3, 1, 32><<<1024, 256, 0, stream>>>(out2, w3p, b3, X);

    // fused recurrence: gates computed in-kernel (gates_k + G traffic deleted)
    lstm_k<<<256, 1024, 0, stream>>>(X, wfp, wbp, whhfp, whhbp,
                                     bih_f, bhh_f, bih_b, bhh_b, flat16);

    // FC head: pack fc1_w (into dead out1 region), split-K MFMA, head
    pack_wf16<<<32768, 256, 0, stream>>>(fc1_w, fc1p, 128, 65536, 32, 65536, 1, 0, 8388608);
    zero_k<<<128, 256, 0, stream>>>(zbuf, 256 * 128);
    fc1m_k<<<dim3(4, 64), 256, 0, stream>>>(flat16, fc1p, zbuf);
    head_k<<<1, 256, 0, stream>>>(zbuf, fc1_b, fs_w, fs_b, out);
}

// Round 10
// 470.058 us; speedup vs baseline: 1.2700x; 1.0818x over previous
//
#include <hip/hip_runtime.h>
#include <hip/hip_fp16.h>

#define BF 256
#define TSTEPS 256

typedef _Float16 h8_t __attribute__((ext_vector_type(8)));
typedef _Float16 h4_t __attribute__((ext_vector_type(4)));
typedef float f4_t __attribute__((ext_vector_type(4)));

union H8 { uint4 u; h8_t v; };
union H4 { uint2 u; h4_t v; };
union U2H4 { uint2 u; __half h[4]; };

// fast sigmoid/tanh: v_exp + v_rcp (error << f16 storage quantization of h)
static __device__ __forceinline__ float sigmoidf_(float x) {
    return __builtin_amdgcn_rcpf(1.f + __expf(-x));
}
static __device__ __forceinline__ float tanhf_(float x) {
    return 1.f - 2.f * __builtin_amdgcn_rcpf(__expf(2.f * x) + 1.f);
}

// xor-32 lane exchange on the VALU (v_permlane32_swap_b32) instead of the LDS
// crossbar (ds_swizzle). Bit-exact vs __shfl_xor(x,32).
static __device__ __forceinline__ float xswap32(float x, int lane) {
    typedef unsigned uv2 __attribute__((ext_vector_type(2)));
    unsigned xu = __float_as_uint(x);
    uv2 r = __builtin_amdgcn_permlane32_swap(xu, xu, false, false);
    return __uint_as_float((lane & 32) ? r[0] : r[1]);
}

// LDS-only workgroup barrier: drains lgkmcnt (ds ops) but leaves vmcnt
// (global stores of h / X prefetch loads) in flight across the barrier.
static __device__ __forceinline__ void wg_barrier_lds() {
    __builtin_amdgcn_sched_barrier(0);
    asm volatile("s_waitcnt lgkmcnt(0)" ::: "memory");
    __builtin_amdgcn_s_barrier();
    __builtin_amdgcn_sched_barrier(0);
}

// ---- pack helper: f16 MFMA operand layout -----------------------------------------
static __device__ __forceinline__ void pack_one(const float* __restrict__ src,
                                                __half* __restrict__ dst,
                                                int OC, int IC, int KS,
                                                int oc_str, int ic_str, int k_str, int i) {
    int grp = KS / 4;
    int j = i % grp;
    int oc = (i / grp) % OC;
    int g = (i / (grp * OC)) & 3;
    int chunk = i / (grp * OC * 4);
    int CPK = IC / KS;
    int cc = chunk % CPK;
    int khw = chunk / CPK;
    int ic = cc * KS + g * grp + j;
    dst[i] = __float2half(src[(long)oc * oc_str + (long)ic * ic_str + khw * k_str]);
}

// Whh/Wih pack with class-interleaved row permutation: packed row prow = T*16+cls*4+du
// maps to original row cls*128 + T*4 + du. A 16-row MFMA tile then holds
// 4 classes x 4 units; wave w (2 tiles) covers units [8w,8w+8) x all 4 classes.
static __device__ __forceinline__ void pack_whh_one(const float* __restrict__ src,
                                                    __half* __restrict__ dst, int i) {
    int j = i & 7;
    int prow = (i >> 3) & 511;
    int cg = i >> 12;            // chunk*4 + g
    int g = cg & 3, chunk = cg >> 2;
    int t = prow >> 4, rr = prow & 15;
    int cls = rr >> 2, du = rr & 3;
    int orig = cls * 128 + t * 4 + du;
    int ic = chunk * 32 + g * 8 + j;
    dst[i] = __float2half(src[orig * 128 + ic]);
}

// ---- fused weight prep ------------------------------------------------------------
// NOTE: Wih is packed class-interleaved (pack_whh_one) since it is consumed as
// the A-operand inside the fused lstm kernel, with the same tile map as Whh.
__global__ __launch_bounds__(256) void prep_k(
        const float* __restrict__ w0, const float* __restrict__ w1,
        const float* __restrict__ w2, const float* __restrict__ w3,
        const float* __restrict__ Wihf, const float* __restrict__ Wihb,
        const float* __restrict__ Whhf, const float* __restrict__ Whhb,
        float* __restrict__ w0t, __half* __restrict__ w1p,
        __half* __restrict__ w2p, __half* __restrict__ w3p,
        __half* __restrict__ wfp, __half* __restrict__ wbp,
        __half* __restrict__ whhfp, __half* __restrict__ whhbp) {
    int i = blockIdx.x * 256 + threadIdx.x;
    if (i < 144) { int oc = i / 9, rem = i % 9; w0t[rem * 16 + oc] = w0[i]; return; }
    i -= 144;
    if (i < 4608) { pack_one(w1, w1p, 32, 16, 16, 144, 9, 1, i); return; }
    i -= 4608;
    if (i < 18432) { pack_one(w2, w2p, 64, 32, 32, 288, 9, 1, i); return; }
    i -= 18432;
    if (i < 73728) { pack_one(w3, w3p, 128, 64, 32, 576, 9, 1, i); return; }
    i -= 73728;
    if (i < 65536) { pack_whh_one(Wihf, wfp, i); return; }
    i -= 65536;
    if (i < 65536) { pack_whh_one(Wihb, wbp, i); return; }
    i -= 65536;
    if (i < 65536) { pack_whh_one(Whhf, whhfp, i); return; }
    i -= 65536;
    if (i < 65536) { pack_whh_one(Whhb, whhbp, i); return; }
}

__global__ void pack_wf16(const float* __restrict__ src, __half* __restrict__ dst,
                          int OC, int IC, int KS,
                          int oc_str, int ic_str, int k_str, int total) {
    int i = blockIdx.x * 256 + threadIdx.x;
    if (i >= total) return;
    pack_one(src, dst, OC, IC, KS, oc_str, ic_str, k_str, i);
}

// ---- conv0: 1->16 ch, VALU, NHWC f16 out (uint4-packed stores) --------------------
__global__ __launch_bounds__(256) void conv0_k(const float* __restrict__ in,
                                               const float* __restrict__ wT,
                                               const float* __restrict__ bias,
                                               __half* __restrict__ out) {
    __shared__ float wsm[9][16];
    __shared__ float bs[16];
    int tid = threadIdx.x;
    if (tid < 144) wsm[tid / 16][tid % 16] = wT[tid];
    if (tid < 16) bs[tid] = bias[tid];
    __syncthreads();
    int gid = blockIdx.x * 256 + tid;
    int ow = gid % 27;
    int t = (gid / 27) % 256;
    int bf = gid / (27 * 256);
    float acc[16];
#pragma unroll
    for (int o = 0; o < 16; o++) acc[o] = bs[o];
    int iw0 = ow * 3 - 1;
#pragma unroll
    for (int kh = 0; kh < 3; kh++) {
        int tt = t + kh - 1;
        if ((unsigned)tt >= 256u) continue;
        const float* ip = in + ((long)bf * 256 + tt) * 81;
#pragma unroll
        for (int kw = 0; kw < 3; kw++) {
            int iw = iw0 + kw;
            if ((unsigned)iw >= 81u) continue;
            float x = ip[iw];
#pragma unroll
            for (int o = 0; o < 16; o++) acc[o] += x * wsm[kh * 3 + kw][o];
        }
    }
    union OU { uint4 u; __half2 h2[4]; } o0, o1;
#pragma unroll
    for (int o = 0; o < 4; o++)
        o0.h2[o] = __floats2half2_rn(fmaxf(acc[2 * o], 0.f), fmaxf(acc[2 * o + 1], 0.f));
#pragma unroll
    for (int o = 0; o < 4; o++)
        o1.h2[o] = __floats2half2_rn(fmaxf(acc[8 + 2 * o], 0.f), fmaxf(acc[9 + 2 * o], 0.f));
    uint4* op = (uint4*)(out + (long)gid * 16);
    op[0] = o0.u;
    op[1] = o1.u;
}

// ---- MFMA implicit-GEMM conv: NHWC f16 in/out -------------------------------------
template<int IC, int OC, int WIN, int WOUT, int KS>
__global__ __launch_bounds__(256) void convM_k(const __half* __restrict__ in,
                                               const __half* __restrict__ wp,
                                               const float* __restrict__ bias,
                                               __half* __restrict__ out) {
    constexpr int NT = OC / 16;
    constexpr int CPK = IC / KS;
    constexpr int NCHUNK = 9 * CPK;
    constexpr int GRP = KS / 4;
    int tid = threadIdx.x;
    int lane = tid & 63;
    int wv = tid >> 6;
    int l15 = lane & 15;
    int g = lane >> 4;
    int m = blockIdx.x * 64 + wv * 16 + l15;
    int ow = m % WOUT;
    int t = (m / WOUT) % 256;
    int bf = m / (WOUT * 256);

    f4_t acc[NT];
#pragma unroll
    for (int nt = 0; nt < NT; nt++)
#pragma unroll
        for (int r = 0; r < 4; r++) acc[nt][r] = 0.f;

#pragma unroll
    for (int chunk = 0; chunk < NCHUNK; chunk++) {
        int khw = chunk / CPK, cc = chunk % CPK;
        int kh = khw / 3;
        int kw = khw - kh * 3;
        int tt = t + kh - 1;
        int iw = ow * 3 + kw - 1;
        bool ok = ((unsigned)tt < 256u) && ((unsigned)iw < (unsigned)WIN);
        long aoff = ok ? (((long)(bf * 256 + tt) * WIN + iw) * IC + cc * KS + g * GRP) : 0;
        if constexpr (KS == 32) {
            H8 af;
            af.u = *(const uint4*)(in + aoff);
            if (!ok) af.u = make_uint4(0u, 0u, 0u, 0u);
#pragma unroll
            for (int nt = 0; nt < NT; nt++) {
                H8 bf8;
                bf8.u = *(const uint4*)(wp + ((long)(chunk * 4 + g) * OC + nt * 16 + l15) * GRP);
                acc[nt] = __builtin_amdgcn_mfma_f32_16x16x32_f16(af.v, bf8.v, acc[nt], 0, 0, 0);
            }
        } else {
            H4 af;
            af.u = *(const uint2*)(in + aoff);
            if (!ok) af.u = make_uint2(0u, 0u);
#pragma unroll
            for (int nt = 0; nt < NT; nt++) {
                H4 bf4;
                bf4.u = *(const uint2*)(wp + ((long)(chunk * 4 + g) * OC + nt * 16 + l15) * GRP);
                acc[nt] = __builtin_amdgcn_mfma_f32_16x16x16f16(af.v, bf4.v, acc[nt], 0, 0, 0);
            }
        }
    }
    int orow = blockIdx.x * 64 + wv * 16 + g * 4;
#pragma unroll
    for (int nt = 0; nt < NT; nt++) {
        int oc = nt * 16 + l15;
        float b = bias[oc];
#pragma unroll
        for (int r = 0; r < 4; r++) {
            float v = fmaxf(acc[nt][r] + b, 0.f);
            out[(long)(orow + r) * OC + oc] = __float2half(v);
        }
    }
}

// ---- FUSED LSTM: gates (Wih@x) computed in-kernel, 8-step windows -----------------
// Same structure as R9, plus:
// (a) X PREFETCH one window ahead: bxr registers are loaded before the current
//     window's 8 steps run, so HBM latency hides under ~14000cy of step work.
//     The lgkm-only barrier leaves these vmcnt loads in flight by design.
// (b) zsc row stride 36 halfs: write banks (18r + 8*g2 + l15/2) mod 32 cover all
//     32 banks with only same-dword lane pairs -> conflict-free stores.
__global__ __launch_bounds__(1024, 4) void lstm_k(const __half* __restrict__ X,
                                                  const __half* __restrict__ wihfp,
                                                  const __half* __restrict__ wihbp,
                                                  const __half* __restrict__ whhfp,
                                                  const __half* __restrict__ whhbp,
                                                  const float* __restrict__ bihf,
                                                  const float* __restrict__ bhhf,
                                                  const float* __restrict__ bihb,
                                                  const float* __restrict__ bhhb,
                                                  __half* __restrict__ flat) {
    int bid = blockIdx.x;
    int dir = bid >> 7;
    int b0 = (bid & 127) * 2;
    const __half* wp  = dir ? whhbp : whhfp;
    const __half* wip = dir ? wihbp : wihfp;
    const float* bA = dir ? bihb : bihf;
    const float* bB = dir ? bhhb : bhhf;
    int tid = threadIdx.x;
    int w = tid >> 6;            // wave 0..15
    int lane = tid & 63;
    int l15 = lane & 15;
    int g2 = lane >> 4;          // class: 0=i, 1=f, 2=g, 3=o
    int chn = l15 >> 3;          // seq within block
    int u8 = l15 & 7;            // unit within wave's 8
    int unit = w * 8 + u8;       // 0..127
    int tsel = (u8 >> 2) & 1;
    int du = u8 & 3;
    int tw = l15 & 7;            // producer col timestep-within-window

    // A-frags: Whh + Wih, each 2 tiles x 4 k-chunks
    H8 afr[2][4], aih[2][4];
#pragma unroll
    for (int t = 0; t < 2; t++) {
        int prow = (w * 2 + t) * 16 + l15;
#pragma unroll
        for (int c = 0; c < 4; c++) {
            afr[t][c].u = *(const uint4*)(wp  + ((long)((c * 4 + g2) * 512 + prow)) * 8);
            aih[t][c].u = *(const uint4*)(wip + ((long)((c * 4 + g2) * 512 + prow)) * 8);
        }
    }
    float cbias = bA[g2 * 128 + unit] + bB[g2 * 128 + unit];

    __shared__ __align__(16) __half hbuf[2][2][128];
    __shared__ __align__(16) __half zsc[16][32][36];   // per-wave z_ih scratch, padded
    if (tid < 256) hbuf[0][tid >> 7][tid & 127] = __float2half(0.f);
    __syncthreads();

    const f4_t zero4 = {0.f, 0.f, 0.f, 0.f};
    float cst = 0.f;                         // cell state, valid on g2==1 lanes
    float ma = (g2 == 2) ? 2.f : 1.f;        // tanh(z) = 2*sigmoid(2z)-1 on g-lanes
    float mb = ma;
    float cb = (g2 == 2) ? -1.f : 0.f;
    long fbase = (long)(b0 + chn) * 65536 + dir * 128 + unit;
    long xrow = (long)(b0 + chn) * 256;

    H8 gc;
    H8 bxr0, bxr1, bxr2, bxr3;               // prefetched X for the NEXT window

    // issue X loads for window wnd (latency hides under the preceding 8 steps)
    auto issueX = [&](int wnd) {
        int tp = dir ? (255 - (wnd * 8 + tw)) : (wnd * 8 + tw);
        const __half* xb = X + (xrow + tp) * 128 + g2 * 8;
        bxr0.u = *(const uint4*)(xb);
        bxr1.u = *(const uint4*)(xb + 32);
        bxr2.u = *(const uint4*)(xb + 64);
        bxr3.u = *(const uint4*)(xb + 96);
    };
    // consume bxr -> z_ih for that window -> zsc -> gc (intra-wave redistribution)
    auto computeW = [&]() {
        f4_t z0, z1;
        z0 = __builtin_amdgcn_mfma_f32_16x16x32_f16(aih[0][0].v, bxr0.v, zero4, 0, 0, 0);
        z1 = __builtin_amdgcn_mfma_f32_16x16x32_f16(aih[1][0].v, bxr0.v, zero4, 0, 0, 0);
        z0 = __builtin_amdgcn_mfma_f32_16x16x32_f16(aih[0][1].v, bxr1.v, z0, 0, 0, 0);
        z1 = __builtin_amdgcn_mfma_f32_16x16x32_f16(aih[1][1].v, bxr1.v, z1, 0, 0, 0);
        z0 = __builtin_amdgcn_mfma_f32_16x16x32_f16(aih[0][2].v, bxr2.v, z0, 0, 0, 0);
        z1 = __builtin_amdgcn_mfma_f32_16x16x32_f16(aih[1][2].v, bxr2.v, z1, 0, 0, 0);
        z0 = __builtin_amdgcn_mfma_f32_16x16x32_f16(aih[0][3].v, bxr3.v, z0, 0, 0, 0);
        z1 = __builtin_amdgcn_mfma_f32_16x16x32_f16(aih[1][3].v, bxr3.v, z1, 0, 0, 0);
        // producer lane holds rows g2*4+r (tile 0/1) for col l15 = chn*8 + tw
#pragma unroll
        for (int r = 0; r < 4; r++) {
            zsc[w][g2 * 4 + r][l15]      = __float2half(z0[r]);
            zsc[w][16 + g2 * 4 + r][l15] = __float2half(z1[r]);
        }
        // LDS ops are in-order per wave: this read sees the writes above.
        gc.u = *(const uint4*)&zsc[w][tsel * 16 + g2 * 4 + du][chn * 8];
    };

    issueX(0);
    computeW();        // window 0 (latency exposed once, prologue only)
    issueX(1);         // in flight during window 0's steps

    for (int to = 0; to < 32; to++) {
#pragma unroll
        for (int ti = 0; ti < 8; ti++) {
            int s = to * 8 + ti;
            int p = s & 1;
            H8 bfr[4];
#pragma unroll
            for (int c = 0; c < 4; c++)
                bfr[c].u = *(const uint4*)(&hbuf[p][chn][c * 32 + g2 * 8]);

            f4_t acc[2];
#pragma unroll
            for (int t = 0; t < 2; t++)
                acc[t] = __builtin_amdgcn_mfma_f32_16x16x32_f16(afr[t][0].v, bfr[0].v,
                                                                zero4, 0, 0, 0);
#pragma unroll
            for (int c = 1; c < 4; c++)
#pragma unroll
                for (int t = 0; t < 2; t++)
                    acc[t] = __builtin_amdgcn_mfma_f32_16x16x32_f16(afr[t][c].v, bfr[c].v,
                                                                    acc[t], 0, 0, 0);
            // select acc[tsel][du]
            f4_t at;
#pragma unroll
            for (int e = 0; e < 4; e++) at[e] = tsel ? acc[1][e] : acc[0][e];
            float lo = (du & 1) ? at[1] : at[0];
            float hi = (du & 1) ? at[3] : at[2];
            float ev = (du & 2) ? hi : lo;

            float z = ev + (float)gc.v[ti] + cbias;
            float a = sigmoidf_(ma * z) * mb + cb;   // i,f,o: sigmoid; g: tanh

            float x1 = xswap32(a, lane);             // i<->g, f<->o (VALU permlane)
            float pi = a * x1;                       // on g2=0: sig(i)*tanh(g)
            float x2 = __shfl_xor(pi, 16, 64);       // g2=1 <- g2=0
            float cn = a * cst + x2;                 // on g2=1: sig(f)*c + pi
            cst = cn;
            float tc = tanhf_(cn);
            float x3 = xswap32(tc, lane);            // g2=3 <- g2=1 (VALU permlane)
            float h = a * x3;                        // on g2=3: sig(o)*tanh(c')

            if (g2 == 3) {
                __half hh = __float2half(h);
                int ts = dir ? (255 - s) : s;
                hbuf[p ^ 1][chn][unit] = hh;
                flat[fbase + (long)ts * 256] = hh;
            }
            wg_barrier_lds();
        }
        if (to < 31) {
            computeW();                 // window to+1 (loads landed ~8 steps ago)
            if (to < 30) issueX(to + 2);// prefetch the following window
        }
    }
}

// ---- FC1 MFMA split-K: z[256][128] += flat16 @ fc1_w16^T --------------------------
__global__ __launch_bounds__(256) void fc1m_k(const __half* __restrict__ flat,
                                              const __half* __restrict__ wp,
                                              float* __restrict__ z) {
    int tid = threadIdx.x;
    int lane = tid & 63;
    int wv = tid >> 6;
    int l15 = lane & 15;
    int g = lane >> 4;
    int m0 = blockIdx.x * 64 + wv * 16;
    long k0 = (long)blockIdx.y * 1024;

    f4_t acc[8];
#pragma unroll
    for (int nt = 0; nt < 8; nt++)
#pragma unroll
        for (int r = 0; r < 4; r++) acc[nt][r] = 0.f;

    for (int c = 0; c < 32; c++) {
        long chunk = (k0 >> 5) + c;
        H8 af;
        af.u = *(const uint4*)(flat + (long)(m0 + l15) * 65536 + k0 + c * 32 + g * 8);
#pragma unroll
        for (int nt = 0; nt < 8; nt++) {
            H8 bw;
            bw.u = *(const uint4*)(wp + ((chunk * 4 + g) * 128 + nt * 16 + l15) * 8);
            acc[nt] = __builtin_amdgcn_mfma_f32_16x16x32_f16(af.v, bw.v, acc[nt], 0, 0, 0);
        }
    }
#pragma unroll
    for (int nt = 0; nt < 8; nt++)
#pragma unroll
        for (int r = 0; r < 4; r++)
            atomicAdd(&z[(m0 + g * 4 + r) * 128 + nt * 16 + l15], acc[nt][r]);
}

__global__ void zero_k(float* __restrict__ p, int n) {
    int i = blockIdx.x * 256 + threadIdx.x;
    if (i < n) p[i] = 0.f;
}

// ---- head -------------------------------------------------------------------------
__global__ __launch_bounds__(256) void head_k(const float* __restrict__ z,
                                              const float* __restrict__ b1,
                                              const float* __restrict__ fsw,
                                              const float* __restrict__ fsb,
                                              float* __restrict__ out) {
    __shared__ float sf[256];
    int r = threadIdx.x;
    float acc = fsb[0];
#pragma unroll
    for (int j4 = 0; j4 < 32; j4++) {
        float4 zv = *(const float4*)&z[r * 128 + j4 * 4];
        float4 bv = *(const float4*)&b1[j4 * 4];
        float4 wv = *(const float4*)&fsw[j4 * 4];
        acc += fmaxf(zv.x + bv.x, 0.f) * wv.x;
        acc += fmaxf(zv.y + bv.y, 0.f) * wv.y;
        acc += fmaxf(zv.z + bv.z, 0.f) * wv.z;
        acc += fmaxf(zv.w + bv.w, 0.f) * wv.w;
    }
    float val = sigmoidf_(acc) * 4.f + 1.f;
    out[16 + r] = val;
    sf[r] = val;
    __syncthreads();
    if (r < 16) {
        float m = 0.f;
#pragma unroll
        for (int f = 0; f < 16; f++) m += sf[r * 16 + f];
        out[r] = m * (1.f / 16.f);
    }
}

extern "C" void kernel_launch(void* const* d_in, const int* in_sizes, int n_in,
                              void* d_out, int out_size, void* d_ws, size_t ws_size,
                              hipStream_t stream) {
    const float* audio = (const float*)d_in[0];
    const float* w0 = (const float*)d_in[2];
    const float* b0 = (const float*)d_in[3];
    const float* w1 = (const float*)d_in[4];
    const float* b1 = (const float*)d_in[5];
    const float* w2 = (const float*)d_in[6];
    const float* b2 = (const float*)d_in[7];
    const float* w3 = (const float*)d_in[8];
    const float* b3 = (const float*)d_in[9];
    const float* Wih_f = (const float*)d_in[10];
    const float* Whh_f = (const float*)d_in[11];
    const float* bih_f = (const float*)d_in[12];
    const float* bhh_f = (const float*)d_in[13];
    const float* Wih_b = (const float*)d_in[14];
    const float* Whh_b = (const float*)d_in[15];
    const float* bih_b = (const float*)d_in[16];
    const float* bhh_b = (const float*)d_in[17];
    const float* fc1_w = (const float*)d_in[18];
    const float* fc1_b = (const float*)d_in[19];
    const float* fs_w = (const float*)d_in[20];
    const float* fs_b = (const float*)d_in[21];
    float* out = (float*)d_out;

    char* ws = (char*)d_ws;
    // lifetimes: out1 dies before fc1p; out0 dies before flat16
    __half* out1  = (__half*)(ws);                    // 37.7 MB
    __half* fc1p  = (__half*)(ws);                    // 16.8 MB (post-lstm)
    __half* flat16= (__half*)(ws + 134217728);        // 33.6 MB
    __half* out0  = (__half*)(ws + 134217728);        // 56.6 MB (pre-flat16)
    __half* X     = (__half*)(ws + 201326592);        // 16.8 MB
    __half* out2  = (__half*)(ws + 218103808);        // 25.2 MB
    char* rd = ws + 243269632;
    float*  w0t   = (float*)(rd);
    __half* w1p   = (__half*)(rd + 1024);
    __half* w2p   = (__half*)(rd + 10240);
    __half* w3p   = (__half*)(rd + 47104);
    __half* wfp   = (__half*)(rd + 194560);
    __half* wbp   = (__half*)(rd + 325632);
    __half* whhfp = (__half*)(rd + 456704);
    __half* whhbp = (__half*)(rd + 587776);
    float*  zbuf  = (float*)(rd + 718848);

    // fused weight prep (1 launch)
    prep_k<<<1403, 256, 0, stream>>>(w0, w1, w2, w3, Wih_f, Wih_b, Whh_f, Whh_b,
                                     w0t, w1p, w2p, w3p, wfp, wbp, whhfp, whhbp);

    // conv chain (NHWC f16)
    conv0_k<<<6912, 256, 0, stream>>>(audio, w0t, b0, out0);
    convM_k<16, 32, 27, 9, 16><<<9216, 256, 0, stream>>>(out0, w1p, b1, out1);
    convM_k<32, 64, 9, 3, 32><<<3072, 256, 0, stream>>>(out1, w2p, b2, out2);
    convM_k<64, 128, 3, 1, 32><<<1024, 256, 0, stream>>>(out2, w3p, b3, X);

    // fused recurrence: gates computed in-kernel, X prefetched one window ahead
    lstm_k<<<256, 1024, 0, stream>>>(X, wfp, wbp, whhfp, whhbp,
                                     bih_f, bhh_f, bih_b, bhh_b, flat16);

    // FC head: pack fc1_w (into dead out1 region), split-K MFMA, head
    pack_wf16<<<32768, 256, 0, stream>>>(fc1_w, fc1p, 128, 65536, 32, 65536, 1, 0, 8388608);
    zero_k<<<128, 256, 0, stream>>>(zbuf, 256 * 128);
    fc1m_k<<<dim3(4, 64), 256, 0, stream>>>(flat16, fc1p, zbuf);
    head_k<<<1, 256, 0, stream>>>(zbuf, fc1_b, fs_w, fs_b, out);
}